// Round 14
// baseline (420.863 us; speedup 1.0000x reference)
//
#include <hip/hip_runtime.h>

typedef __attribute__((ext_vector_type(8))) short bf16x8;
typedef __attribute__((ext_vector_type(4))) float f32x4;
typedef unsigned short u16;
typedef unsigned int u32;

constexpr int kB = 4, kL = 2048, kD = 1024, kH = 16, kDK = 64;
constexpr int kR = kB * kL;
constexpr long kWrelMax = 2 * kL - 2;   // 4094 = last valid w_rel row
constexpr float kQScale = 0.125f * 1.44269504088896f;  // 1/sqrt(dk) * log2(e)

__device__ inline float fexp2(float x) { return __builtin_amdgcn_exp2f(x); }

__device__ inline u16 f2bf(float x) {
    union { float f; u32 u; } v; v.f = x;
    u32 r = v.u + 0x7FFFu + ((v.u >> 16) & 1u);   // RNE
    return (u16)(r >> 16);
}
// trunc split: hi = trunc_bf16(x), lo = trunc_bf16(x - hi)
__device__ inline void splitf(float x, u16& hi, u16& lo) {
    union { float f; u32 u; } v; v.f = x;
    u32 hu = v.u & 0xFFFF0000u;
    hi = (u16)(hu >> 16);
    union { u32 u; float f; } hf; hf.u = hu;
    union { float f; u32 u; } l; l.f = x - hf.f;
    lo = (u16)(l.u >> 16);
}
__device__ inline f32x4 MFMA(bf16x8 a, bf16x8 b, f32x4 c) {
    return __builtin_amdgcn_mfma_f32_16x16x32_bf16(a, b, c, 0, 0, 0);
}
// async global->LDS, 16B per lane; LDS dest = wave-uniform base + lane*16
__device__ __forceinline__ void gll16(const u16* g, u16* l) {
    __builtin_amdgcn_global_load_lds(
        (const __attribute__((address_space(1))) u32*)g,
        (__attribute__((address_space(3))) u32*)l, 16, 0, 0);
}

// ---------------------------------------------------------------------------
// K1: fp32 -> bf16 hi/lo split; 4 tensors in one launch (blockIdx.y selects)
// ---------------------------------------------------------------------------
__global__ void split4x4_kernel(const float* __restrict__ i0, const float* __restrict__ i1,
                                const float* __restrict__ i2, const float* __restrict__ i3,
                                u16* __restrict__ h0, u16* __restrict__ h1,
                                u16* __restrict__ h2, u16* __restrict__ h3,
                                u16* __restrict__ l0, u16* __restrict__ l1,
                                u16* __restrict__ l2, u16* __restrict__ l3, int n4) {
    int idx = blockIdx.x * blockDim.x + threadIdx.x;
    if (idx >= n4) return;
    const float* in = blockIdx.y == 0 ? i0 : blockIdx.y == 1 ? i1 : blockIdx.y == 2 ? i2 : i3;
    u16* hi = blockIdx.y == 0 ? h0 : blockIdx.y == 1 ? h1 : blockIdx.y == 2 ? h2 : h3;
    u16* lo = blockIdx.y == 0 ? l0 : blockIdx.y == 1 ? l1 : blockIdx.y == 2 ? l2 : l3;
    float4 x = reinterpret_cast<const float4*>(in)[idx];
    ushort4 h, l;
    splitf(x.x, h.x, l.x); splitf(x.y, h.y, l.y);
    splitf(x.z, h.z, l.z); splitf(x.w, h.w, l.w);
    reinterpret_cast<ushort4*>(hi)[idx] = h;
    reinterpret_cast<ushort4*>(lo)[idx] = l;
}
__global__ void split4_kernel(const float* __restrict__ in,
                              u16* __restrict__ hi, u16* __restrict__ lo, int n4) {
    int idx = blockIdx.x * blockDim.x + threadIdx.x;
    if (idx >= n4) return;
    float4 x = reinterpret_cast<const float4*>(in)[idx];
    ushort4 h, l;
    splitf(x.x, h.x, l.x); splitf(x.y, h.y, l.y);
    splitf(x.z, h.z, l.z); splitf(x.w, h.w, l.w);
    reinterpret_cast<ushort4*>(hi)[idx] = h;
    reinterpret_cast<ushort4*>(lo)[idx] = l;
}

// ---------------------------------------------------------------------------
// K2: merged Q/K/V projection GEMM (blockIdx.z selects). 2-term exact-A.
//  B staged via global_load_lds (source-side chunk XOR: physical=logical^(row&3),
//  identical to the read formula); A fp32->split reg path, double-buffered;
//  ONE barrier per K-step.
// ---------------------------------------------------------------------------
__global__ __launch_bounds__(256) void proj3(
    const float* __restrict__ Aq, const float* __restrict__ Ak, const float* __restrict__ Av,
    const u16* __restrict__ Bqh, const u16* __restrict__ Bkh, const u16* __restrict__ Bvh,
    const float* __restrict__ bq, const float* __restrict__ bk, const float* __restrict__ bv,
    u16* __restrict__ Yq, u16* __restrict__ Yk, u16* __restrict__ Yv)
{
    __shared__ __align__(16) u16 Ash[2][128 * 32], Asl[2][128 * 32];
    __shared__ __align__(16) u16 Bsh[2][128 * 32];

    const int z = blockIdx.z;
    const float* Af32 = z == 0 ? Aq : z == 1 ? Ak : Av;
    const u16* Bgh    = z == 0 ? Bqh : z == 1 ? Bkh : Bvh;
    const float* bias = z == 0 ? bq : z == 1 ? bk : bv;
    u16* Yh           = z == 0 ? Yq : z == 1 ? Yk : Yv;
    const float scale = z == 0 ? kQScale : 1.0f;

    const int tid = threadIdx.x;
    const int row0 = blockIdx.x * 128, col0 = blockIdx.y * 128;
    const int w = tid >> 6, lane = tid & 63;
    const int s = lane & 15, g = lane >> 4;
    const int wrow = w >> 1, wcol = w & 1;
    const int srow = tid >> 1;
    const int skq  = (tid & 1) * 16;

    // gll staging geometry for B: per it, row = w*32+it*16+(lane>>2),
    // physical chunk = lane&3, logical chunk cl = (lane&3)^(row&3).
    const u16* bsrc[2];
    #pragma unroll
    for (int it = 0; it < 2; ++it) {
        int row = w * 32 + it * 16 + (lane >> 2);
        int cl = (lane & 3) ^ (row & 3);
        bsrc[it] = &Bgh[(size_t)(col0 + row) * kD + cl * 8];
    }
    auto gllB = [&](int buf, int k0) {
        #pragma unroll
        for (int it = 0; it < 2; ++it)
            gll16(bsrc[it] + k0, &Bsh[buf][(w * 128 + it * 64) * 8]);
    };

    const f32x4 fz = {0.f, 0.f, 0.f, 0.f};
    f32x4 acc[4][4];
    #pragma unroll
    for (int m = 0; m < 4; ++m)
        #pragma unroll
        for (int n = 0; n < 4; ++n) acc[m][n] = fz;

    float4 aR[4];
    auto loadA = [&](int k0) {
        const float* p = &Af32[(size_t)(row0 + srow) * kD + k0 + skq];
        aR[0] = *(const float4*)(p);
        aR[1] = *(const float4*)(p + 4);
        aR[2] = *(const float4*)(p + 8);
        aR[3] = *(const float4*)(p + 12);
    };
    auto writeA = [&](int buf) {
        const int c0 = skq >> 3, sw = srow & 3;
        bf16x8 h0, h1, l0, l1;
        const float* af = (const float*)aR;
        #pragma unroll
        for (int q = 0; q < 8; ++q) {
            u16 hh, ll;
            splitf(af[q], hh, ll);     h0[q] = (short)hh; l0[q] = (short)ll;
            splitf(af[8 + q], hh, ll); h1[q] = (short)hh; l1[q] = (short)ll;
        }
        *(bf16x8*)&Ash[buf][srow * 32 + (((c0    ) ^ sw) << 3)] = h0;
        *(bf16x8*)&Ash[buf][srow * 32 + (((c0 + 1) ^ sw) << 3)] = h1;
        *(bf16x8*)&Asl[buf][srow * 32 + (((c0    ) ^ sw) << 3)] = l0;
        *(bf16x8*)&Asl[buf][srow * 32 + (((c0 + 1) ^ sw) << 3)] = l1;
    };

    // prologue: stage k=0 (A regs->LDS, B gll), preload A regs for k=32
    loadA(0);
    gllB(0, 0);
    writeA(0);
    loadA(32);
    __syncthreads();

    for (int k0 = 0; k0 < kD; k0 += 32) {
        const int cur = (k0 >> 5) & 1, nxt = cur ^ 1;
        if (k0 + 32 < kD) gllB(nxt, k0 + 32);   // async, drained at end sync

        bf16x8 fAh[4], fAl[4], fBh[4];
        #pragma unroll
        for (int m = 0; m < 4; ++m) {
            int ar = wrow * 64 + m * 16 + s;
            int off = ar * 32 + ((g ^ (ar & 3)) << 3);
            fAh[m] = *(const bf16x8*)&Ash[cur][off];
            fAl[m] = *(const bf16x8*)&Asl[cur][off];
        }
        #pragma unroll
        for (int n = 0; n < 4; ++n) {
            int bc = wcol * 64 + n * 16 + s;
            int off = bc * 32 + ((g ^ (bc & 3)) << 3);
            fBh[n] = *(const bf16x8*)&Bsh[cur][off];
        }
        #pragma unroll
        for (int m = 0; m < 4; ++m)
            #pragma unroll
            for (int n = 0; n < 4; ++n) {
                acc[m][n] = MFMA(fAh[m], fBh[n], acc[m][n]);
                acc[m][n] = MFMA(fAl[m], fBh[n], acc[m][n]);
            }

        if (k0 + 32 < kD) writeA(nxt);          // aR holds k0+32
        if (k0 + 64 < kD) loadA(k0 + 64);
        __syncthreads();
    }

    #pragma unroll
    for (int n = 0; n < 4; ++n) {
        const int colg = col0 + wcol * 64 + n * 16 + s;
        const float bv = bias[colg];
        #pragma unroll
        for (int m = 0; m < 4; ++m) {
            const int rowg = row0 + wrow * 64 + m * 16 + (g << 2);
            if (z == 2) {
                const int b = rowg >> 11, i = rowg & (kL - 1);
                const int h = colg >> 6, d = colg & 63;
                ushort4 o4;
                o4.x = f2bf(acc[m][n][0] + bv);
                o4.y = f2bf(acc[m][n][1] + bv);
                o4.z = f2bf(acc[m][n][2] + bv);
                o4.w = f2bf(acc[m][n][3] + bv);
                *(ushort4*)&Yh[(((size_t)b * kH + h) * kDK + d) * kL + i] = o4;
            } else {
                #pragma unroll
                for (int r = 0; r < 4; ++r) {
                    float val = (acc[m][n][r] + bv) * scale;
                    const int rg = rowg + r;
                    const int b = rg >> 11, i = rg & (kL - 1);
                    const int h = colg >> 6, d = colg & 63;
                    Yh[(((size_t)b * kH + h) * kL + i) * kDK + d] = f2bf(val);
                }
            }
        }
    }
}

// ---------------------------------------------------------------------------
// K4: output GEMM  out = concat @ Wo^T + bo  (3-term, fp32 out)
//  ALL four panels staged via global_load_lds (pre-split bf16), dbuf,
//  one barrier per K-step, zero staging VALU.
// ---------------------------------------------------------------------------
__global__ __launch_bounds__(256) void out_gemm(
    const u16* __restrict__ Agh, const u16* __restrict__ Agl,
    const u16* __restrict__ Bgh, const u16* __restrict__ Bgl,
    const float* __restrict__ bias, float* __restrict__ Yf)
{
    __shared__ __align__(16) u16 Ash[2][128 * 32], Asl[2][128 * 32];
    __shared__ __align__(16) u16 Bsh[2][128 * 32], Bsl[2][128 * 32];

    const int tid = threadIdx.x;
    const int row0 = blockIdx.x * 128, col0 = blockIdx.y * 128;
    const int w = tid >> 6, lane = tid & 63;
    const int s = lane & 15, g = lane >> 4;
    const int wrow = w >> 1, wcol = w & 1;

    // gll geometry: row = w*32+it*16+(lane>>2); logical chunk = (lane&3)^(row&3)
    const u16* srcAh[2]; const u16* srcAl[2];
    const u16* srcBh[2]; const u16* srcBl[2];
    #pragma unroll
    for (int it = 0; it < 2; ++it) {
        int row = w * 32 + it * 16 + (lane >> 2);
        int cl = (lane & 3) ^ (row & 3);
        size_t oa = (size_t)(row0 + row) * kD + cl * 8;
        size_t ob = (size_t)(col0 + row) * kD + cl * 8;
        srcAh[it] = Agh + oa; srcAl[it] = Agl + oa;
        srcBh[it] = Bgh + ob; srcBl[it] = Bgl + ob;
    }
    auto gll4 = [&](int buf, int k0) {
        #pragma unroll
        for (int it = 0; it < 2; ++it) {
            u16* d = (u16*)((w * 128 + it * 64) * 8);
            gll16(srcAh[it] + k0, &Ash[buf][(w * 128 + it * 64) * 8]);
            gll16(srcAl[it] + k0, &Asl[buf][(w * 128 + it * 64) * 8]);
            gll16(srcBh[it] + k0, &Bsh[buf][(w * 128 + it * 64) * 8]);
            gll16(srcBl[it] + k0, &Bsl[buf][(w * 128 + it * 64) * 8]);
            (void)d;
        }
    };

    const f32x4 fz = {0.f, 0.f, 0.f, 0.f};
    f32x4 acc[4][4];
    #pragma unroll
    for (int m = 0; m < 4; ++m)
        #pragma unroll
        for (int n = 0; n < 4; ++n) acc[m][n] = fz;

    gll4(0, 0);
    __syncthreads();

    for (int k0 = 0; k0 < kD; k0 += 32) {
        const int cur = (k0 >> 5) & 1, nxt = cur ^ 1;
        if (k0 + 32 < kD) gll4(nxt, k0 + 32);

        bf16x8 fAh[4], fAl[4], fBh[4], fBl[4];
        #pragma unroll
        for (int m = 0; m < 4; ++m) {
            int ar = wrow * 64 + m * 16 + s;
            int off = ar * 32 + ((g ^ (ar & 3)) << 3);
            fAh[m] = *(const bf16x8*)&Ash[cur][off];
            fAl[m] = *(const bf16x8*)&Asl[cur][off];
        }
        #pragma unroll
        for (int n = 0; n < 4; ++n) {
            int bc = wcol * 64 + n * 16 + s;
            int off = bc * 32 + ((g ^ (bc & 3)) << 3);
            fBh[n] = *(const bf16x8*)&Bsh[cur][off];
            fBl[n] = *(const bf16x8*)&Bsl[cur][off];
        }
        #pragma unroll
        for (int m = 0; m < 4; ++m)
            #pragma unroll
            for (int n = 0; n < 4; ++n) {
                acc[m][n] = MFMA(fAh[m], fBh[n], acc[m][n]);
                acc[m][n] = MFMA(fAl[m], fBh[n], acc[m][n]);
                acc[m][n] = MFMA(fAh[m], fBl[n], acc[m][n]);
            }
        __syncthreads();
    }

    #pragma unroll
    for (int n = 0; n < 4; ++n) {
        const int colg = col0 + wcol * 64 + n * 16 + s;
        const float bv = bias[colg];
        #pragma unroll
        for (int m = 0; m < 4; ++m) {
            const int rowg = row0 + wrow * 64 + m * 16 + (g << 2);
            #pragma unroll
            for (int r = 0; r < 4; ++r)
                Yf[(size_t)(rowg + r) * kD + colg] = acc[m][n][r] + bv;
        }
    }
}

// ---------------------------------------------------------------------------
// K3: flash attention (R12 structure, verified) + XCD-aware bijective block
//     swizzle: logical = (phys%8)*256 + phys/8 so the 32 i-tile blocks that
//     share a bh's K/V land on the same XCD's L2.
// ---------------------------------------------------------------------------
__global__ __launch_bounds__(256, 2) void attn3(
    const u16* __restrict__ Qh,
    const u16* __restrict__ Kg, const u16* __restrict__ VT,
    const u16* __restrict__ Wr,
    u16* __restrict__ Ch, u16* __restrict__ Cl)
{
    __shared__ __align__(16) u16 Ksh[2][64 * 64];   // [j][d] swizzled     16 KB
    __shared__ __align__(16) u16 Vsh[2][64 * 64];   // V^T [d][j] swizzled 16 KB
    __shared__ __align__(16) u16 Wsh[2][64 * 64];   // [u_loc][d] swizzled 16 KB
    __shared__ __align__(16) u16 Ps[4][16 * 64];    // per-wave P[i][j]     8 KB
    __shared__ __align__(16) u16 Tb[64 * 132];      // bias [il][key]    16.5 KB

    const int tid = threadIdx.x;
    const int w = tid >> 6, lane = tid & 63;
    const int s = lane & 15, g = lane >> 4;
    const int pb = blockIdx.x + 32 * blockIdx.y;    // physical block id
    const int lb = (pb & 7) * 256 + (pb >> 3);      // bijective XCD swizzle
    const int bh = lb >> 5, i0 = (lb & 31) * 64;
    const int b = bh >> 4, h = bh & 15;

    const int srow = tid >> 3;      // staging: dest row (tid>>3)+32*it
    const int sc = tid & 7;         // dest 16B chunk

    auto stageK = [&](int buf, int t) {
        const u16* base = Kg + ((size_t)bh * kL + (size_t)t * 64) * kDK;
        #pragma unroll
        for (int it = 0; it < 2; ++it) {
            int r = srow + it * 32;
            gll16(base + r * 64 + ((sc ^ (r & 7)) << 3), &Ksh[buf][it * 2048 + w * 512]);
        }
    };
    auto stageV = [&](int buf, int t) {
        #pragma unroll
        for (int it = 0; it < 2; ++it) {
            int d = srow + it * 32;
            const u16* src = VT + ((size_t)bh * kDK + d) * kL + t * 64 + ((sc ^ (d & 7)) << 3);
            gll16(src, &Vsh[buf][it * 2048 + w * 512]);
        }
    };
    auto stageW = [&](int buf, int c) {
        #pragma unroll
        for (int it = 0; it < 2; ++it) {
            int r = srow + it * 32;
            long row = (long)i0 + 64L * c + r;
            if (row > kWrelMax) row = kWrelMax;
            gll16(Wr + row * 64 + ((sc ^ (r & 7)) << 3), &Wsh[buf][it * 2048 + w * 512]);
        }
    };

    // ---- hoisted LDS fragment offsets ----
    int foff[4][2];                 // K/V/W fragment reads
    #pragma unroll
    for (int n = 0; n < 4; ++n)
        #pragma unroll
        for (int ks = 0; ks < 2; ++ks) {
            int row = n * 16 + s;
            foff[n][ks] = row * 64 + (((ks * 4 + g) ^ (row & 7)) << 3);
        }
    int prd[2];                     // Ps A-fragment reads (rows i=s)
    #pragma unroll
    for (int ks = 0; ks < 2; ++ks)
        prd[ks] = s * 64 + (((ks * 4 + g) ^ (s & 7)) << 3);
    int pwr[4];                     // Ps b64 writes: row i=s, j=16jn+4g..+3
    #pragma unroll
    for (int jn = 0; jn < 4; ++jn) {
        int c = 2 * jn + (g >> 1);
        pwr[jn] = s * 64 + ((c ^ (s & 7)) << 3) + (g & 1) * 4;
    }

    // Q fragments (pre-scaled by 0.125*log2e in projection)
    const size_t qbase = ((size_t)bh * kL + i0 + w * 16 + s) * kDK + g * 8;
    bf16x8 qh[2];
    qh[0] = *(const bf16x8*)&Qh[qbase];
    qh[1] = *(const bf16x8*)&Qh[qbase + 32];

    const f32x4 fz = {0.f, 0.f, 0.f, 0.f};
    const int ilS = w * 16 + s;       // Tb read row
    const int ilw = w * 16 + g * 4;   // Tb write base row

    // T-gemm: T[il][u] stored at Tb[il][key=(u_loc-il)&127]; rows wave-private
    auto computeT = [&](int c, int buf) {
        f32x4 tacc[4];
        #pragma unroll
        for (int un = 0; un < 4; ++un) {
            bf16x8 wf0 = *(const bf16x8*)&Wsh[buf][foff[un][0]];
            bf16x8 wf1 = *(const bf16x8*)&Wsh[buf][foff[un][1]];
            tacc[un] = MFMA(qh[0], wf0, fz);
            tacc[un] = MFMA(qh[1], wf1, tacc[un]);
        }
        const int cb = c * 64 - w * 16 + s - g * 4;
        #pragma unroll
        for (int un = 0; un < 4; ++un)
            #pragma unroll
            for (int r = 0; r < 4; ++r) {
                int key = (cb + un * 16 - r) & 127;
                Tb[(ilw + r) * 132 + key] =
                    (u16)(__float_as_uint(tacc[un][r]) >> 16);
            }
    };

    f32x4 sacc[4];
    auto loadBias = [&](int t) {
        #pragma unroll
        for (int jn = 0; jn < 4; ++jn) {
            int kb = (t * 64 + jn * 16 + g * 4) & 127;   // 4-aligned
            uint2 tw = *(const uint2*)&Tb[ilS * 132 + kb];
            sacc[jn][0] = __uint_as_float(tw.x << 16);
            sacc[jn][1] = __uint_as_float(tw.x & 0xFFFF0000u);
            sacc[jn][2] = __uint_as_float(tw.y << 16);
            sacc[jn][3] = __uint_as_float(tw.y & 0xFFFF0000u);
        }
    };

    bf16x8 ones;
    #pragma unroll
    for (int q = 0; q < 8; ++q) ones[q] = (short)0x3F80;

    // prologue
    stageK(0, 0); stageV(0, 0); stageW(0, 0); stageW(1, 1);
    __syncthreads();                        // W0,W1,K0,V0 landed
    computeT(0, 0); computeT(1, 1);
    loadBias(0);                            // own-wave rows, program-ordered
    __syncthreads();                        // all waves done reading Wsh[0/1]
    stageW(0, 2);                           // chunk 2 into buf 0
    __syncthreads();                        // chunk-2 W landed

    f32x4 oacc[4] = {fz, fz, fz, fz};
    f32x4 lacc = fz;

    for (int t = 0; t < 32; ++t) {
        const int cur = t & 1, nxt = cur ^ 1;
        if (t < 31) { stageK(nxt, t + 1); stageV(nxt, t + 1); }
        if (t < 30) stageW(nxt, t + 3);     // buf (t+3)&1 == nxt
        if (t < 31) computeT(t + 2, cur);   // chunk t+2 staged at t-1 into buf t&1

        // ---- S^T = K Q^T + bias (sacc preloaded last tile) ----
        __builtin_amdgcn_s_setprio(1);
        #pragma unroll
        for (int jn = 0; jn < 4; ++jn)
            #pragma unroll
            for (int ks = 0; ks < 2; ++ks) {
                bf16x8 kf = *(const bf16x8*)&Ksh[cur][foff[jn][ks]];
                sacc[jn] = MFMA(kf, qh[ks], sacc[jn]);
            }
        __builtin_amdgcn_s_setprio(0);

        // ---- p = exp2(s); trunc-pack pairs; one b64 write per jn ----
        #pragma unroll
        for (int jn = 0; jn < 4; ++jn) {
            u32 a0 = __float_as_uint(fexp2(sacc[jn][0])) & 0xFFFF0000u;
            u32 a1 = __float_as_uint(fexp2(sacc[jn][1])) & 0xFFFF0000u;
            u32 a2 = __float_as_uint(fexp2(sacc[jn][2])) & 0xFFFF0000u;
            u32 a3 = __float_as_uint(fexp2(sacc[jn][3])) & 0xFFFF0000u;
            uint2 pw;
            pw.x = a1 | (a0 >> 16);   // lo u16 = p0 (col j), hi u16 = p1
            pw.y = a3 | (a2 >> 16);
            *(uint2*)&Ps[w][pwr[jn]] = pw;
        }

        // ---- prefetch next tile's bias into sacc (dead after exp2) ----
        if (t < 31) loadBias(t + 1);

        // ---- O += P V;  l += P * ones ----
        __builtin_amdgcn_s_setprio(1);
        #pragma unroll
        for (int ks = 0; ks < 2; ++ks) {
            bf16x8 pf = *(const bf16x8*)&Ps[w][prd[ks]];
            lacc = MFMA(pf, ones, lacc);
            #pragma unroll
            for (int dn = 0; dn < 4; ++dn) {
                bf16x8 vf = *(const bf16x8*)&Vsh[cur][foff[dn][ks]];
                oacc[dn] = MFMA(pf, vf, oacc[dn]);
            }
        }
        __builtin_amdgcn_s_setprio(0);
        __syncthreads();   // drains gll issued this tile; releases cur bufs
    }

    // ---- epilogue: lacc[r] is already l[i = w*16 + g*4 + r] ----
    float invr[4];
    #pragma unroll
    for (int r = 0; r < 4; ++r) invr[r] = 1.0f / lacc[r];

    #pragma unroll
    for (int dn = 0; dn < 4; ++dn)
        #pragma unroll
        for (int r = 0; r < 4; ++r) {
            const int ig = i0 + w * 16 + g * 4 + r;
            float val = oacc[dn][r] * invr[r];
            u16 hh, ll; splitf(val, hh, ll);
            size_t o = ((size_t)(b * kL + ig)) * kD + h * kDK + dn * 16 + s;
            Ch[o] = hh; Cl[o] = ll;
        }
}

// ---------------------------------------------------------------------------
extern "C" void kernel_launch(void* const* d_in, const int* in_sizes, int n_in,
                              void* d_out, int out_size, void* d_ws, size_t ws_size,
                              hipStream_t stream) {
    const float* q    = (const float*)d_in[0];
    const float* k    = (const float*)d_in[1];
    const float* v    = (const float*)d_in[2];
    const float* Wq   = (const float*)d_in[3];
    const float* bq   = (const float*)d_in[4];
    const float* Wk   = (const float*)d_in[5];
    const float* bk   = (const float*)d_in[6];
    const float* Wv   = (const float*)d_in[7];
    const float* bv   = (const float*)d_in[8];
    const float* Wo   = (const float*)d_in[9];
    const float* bo   = (const float*)d_in[10];
    const float* wrel = (const float*)d_in[11];
    float* out = (float*)d_out;

    u16* p = (u16*)d_ws;
    const size_t nW = (size_t)kD * kD;
    const size_t nR = (size_t)(2 * kL - 1) * kDK;
    const size_t nT = (size_t)kB * kL * kD;
    u16* wqh = p; p += nW;  u16* wql = p; p += nW;
    u16* wkh = p; p += nW;  u16* wkl = p; p += nW;
    u16* wvh = p; p += nW;  u16* wvl = p; p += nW;
    u16* woh = p; p += nW;  u16* wol = p; p += nW;
    u16* wrh = p; p += nR;  u16* wrl = p; p += nR;
    u16* qhh = p; p += nT;
    u16* khh = p; p += nT;
    u16* vT  = p; p += nT;
    u16* cch = p; p += nT;  u16* ccl = p; p += nT;

    // K1: weight splits (4 fused) + w_rel split
    hipLaunchKernelGGL(split4x4_kernel, dim3(1024, 4), dim3(256), 0, stream,
                       Wq, Wk, Wv, Wo, wqh, wkh, wvh, woh, wql, wkl, wvl, wol,
                       (int)(nW / 4));
    hipLaunchKernelGGL(split4_kernel, dim3(256), dim3(256), 0, stream,
                       wrel, wrh, wrl, (int)(nR / 4));

    dim3 blk(256);
    // K2: merged Q/K/V projections
    hipLaunchKernelGGL(proj3, dim3(kR / 128, kD / 128, 3), blk, 0, stream,
                       q, k, v, wqh, wkh, wvh, bq, bk, bv, qhh, khh, vT);

    // K3: attention
    hipLaunchKernelGGL(attn3, dim3(kL / 64, kB * kH), blk, 0, stream,
                       qhh, khh, vT, wrh, cch, ccl);

    // K4: output projection
    hipLaunchKernelGGL(out_gemm, dim3(kR / 128, kD / 128), blk, 0, stream,
                       cch, ccl, woh, wol, bo, out);
}

// Round 15
// 393.694 us; speedup vs baseline: 1.0690x; 1.0690x over previous
//
#include <hip/hip_runtime.h>

typedef __attribute__((ext_vector_type(8))) short bf16x8;
typedef __attribute__((ext_vector_type(4))) float f32x4;
typedef unsigned short u16;
typedef unsigned int u32;

constexpr int kB = 4, kL = 2048, kD = 1024, kH = 16, kDK = 64;
constexpr int kR = kB * kL;
constexpr long kWrelMax = 2 * kL - 2;   // 4094 = last valid w_rel row
constexpr float kQScale = 0.125f * 1.44269504088896f;  // 1/sqrt(dk) * log2(e)

__device__ inline float fexp2(float x) { return __builtin_amdgcn_exp2f(x); }

__device__ inline u16 f2bf(float x) {
    union { float f; u32 u; } v; v.f = x;
    u32 r = v.u + 0x7FFFu + ((v.u >> 16) & 1u);   // RNE
    return (u16)(r >> 16);
}
// trunc split: hi = trunc_bf16(x), lo = trunc_bf16(x - hi)
__device__ inline void splitf(float x, u16& hi, u16& lo) {
    union { float f; u32 u; } v; v.f = x;
    u32 hu = v.u & 0xFFFF0000u;
    hi = (u16)(hu >> 16);
    union { u32 u; float f; } hf; hf.u = hu;
    union { float f; u32 u; } l; l.f = x - hf.f;
    lo = (u16)(l.u >> 16);
}
__device__ inline f32x4 MFMA(bf16x8 a, bf16x8 b, f32x4 c) {
    return __builtin_amdgcn_mfma_f32_16x16x32_bf16(a, b, c, 0, 0, 0);
}
// async global->LDS, 16B per lane; LDS dest = wave-uniform base + lane*16
__device__ __forceinline__ void gll16(const u16* g, u16* l) {
    __builtin_amdgcn_global_load_lds(
        (const __attribute__((address_space(1))) u32*)g,
        (__attribute__((address_space(3))) u32*)l, 16, 0, 0);
}

// ---------------------------------------------------------------------------
// K1: fp32 -> bf16 hi/lo split; 4 tensors in one launch (blockIdx.y selects)
// ---------------------------------------------------------------------------
__global__ void split4x4_kernel(const float* __restrict__ i0, const float* __restrict__ i1,
                                const float* __restrict__ i2, const float* __restrict__ i3,
                                u16* __restrict__ h0, u16* __restrict__ h1,
                                u16* __restrict__ h2, u16* __restrict__ h3,
                                u16* __restrict__ l0, u16* __restrict__ l1,
                                u16* __restrict__ l2, u16* __restrict__ l3, int n4) {
    int idx = blockIdx.x * blockDim.x + threadIdx.x;
    if (idx >= n4) return;
    const float* in = blockIdx.y == 0 ? i0 : blockIdx.y == 1 ? i1 : blockIdx.y == 2 ? i2 : i3;
    u16* hi = blockIdx.y == 0 ? h0 : blockIdx.y == 1 ? h1 : blockIdx.y == 2 ? h2 : h3;
    u16* lo = blockIdx.y == 0 ? l0 : blockIdx.y == 1 ? l1 : blockIdx.y == 2 ? l2 : l3;
    float4 x = reinterpret_cast<const float4*>(in)[idx];
    ushort4 h, l;
    splitf(x.x, h.x, l.x); splitf(x.y, h.y, l.y);
    splitf(x.z, h.z, l.z); splitf(x.w, h.w, l.w);
    reinterpret_cast<ushort4*>(hi)[idx] = h;
    reinterpret_cast<ushort4*>(lo)[idx] = l;
}
__global__ void split4_kernel(const float* __restrict__ in,
                              u16* __restrict__ hi, u16* __restrict__ lo, int n4) {
    int idx = blockIdx.x * blockDim.x + threadIdx.x;
    if (idx >= n4) return;
    float4 x = reinterpret_cast<const float4*>(in)[idx];
    ushort4 h, l;
    splitf(x.x, h.x, l.x); splitf(x.y, h.y, l.y);
    splitf(x.z, h.z, l.z); splitf(x.w, h.w, l.w);
    reinterpret_cast<ushort4*>(hi)[idx] = h;
    reinterpret_cast<ushort4*>(lo)[idx] = l;
}

// ---------------------------------------------------------------------------
// K2: merged Q/K/V projection GEMM (blockIdx.z selects). 2-term exact-A.
//  R12-proven reg-staged structure (2 barriers/K-step, loads 1 iter ahead)
//  + XCD chunked block swizzle (512 blocks/slice, 64/XCD = one col panel).
// ---------------------------------------------------------------------------
__global__ __launch_bounds__(256) void proj3(
    const float* __restrict__ Aq, const float* __restrict__ Ak, const float* __restrict__ Av,
    const u16* __restrict__ Bqh, const u16* __restrict__ Bkh, const u16* __restrict__ Bvh,
    const float* __restrict__ bq, const float* __restrict__ bk, const float* __restrict__ bv,
    u16* __restrict__ Yq, u16* __restrict__ Yk, u16* __restrict__ Yv)
{
    __shared__ __align__(16) u16 Ash[128 * 32], Asl[128 * 32];
    __shared__ __align__(16) u16 Bsh[128 * 32];

    const int z = blockIdx.z;
    const float* Af32 = z == 0 ? Aq : z == 1 ? Ak : Av;
    const u16* Bgh    = z == 0 ? Bqh : z == 1 ? Bkh : Bvh;
    const float* bias = z == 0 ? bq : z == 1 ? bk : bv;
    u16* Yh           = z == 0 ? Yq : z == 1 ? Yk : Yv;
    const float scale = z == 0 ? kQScale : 1.0f;

    const int tid = threadIdx.x;
    // XCD chunked swizzle: 512 blocks/slice; XCD p%8 gets 64 consecutive lb
    const int pb = blockIdx.x + 64 * blockIdx.y;
    const int lb = (pb & 7) * 64 + (pb >> 3);
    const int row0 = (lb & 63) * 128, col0 = (lb >> 6) * 128;
    const int w = tid >> 6, lane = tid & 63;
    const int s = lane & 15, g = lane >> 4;
    const int wrow = w >> 1, wcol = w & 1;
    const int srow = tid >> 1;
    const int skq  = (tid & 1) * 16;

    const f32x4 fz = {0.f, 0.f, 0.f, 0.f};
    f32x4 acc[4][4];
    #pragma unroll
    for (int m = 0; m < 4; ++m)
        #pragma unroll
        for (int n = 0; n < 4; ++n) acc[m][n] = fz;

    float4 aR[4];
    bf16x8 bRh[2];

    auto loadA = [&](int k0) {
        const float* p = &Af32[(size_t)(row0 + srow) * kD + k0 + skq];
        aR[0] = *(const float4*)(p);
        aR[1] = *(const float4*)(p + 4);
        aR[2] = *(const float4*)(p + 8);
        aR[3] = *(const float4*)(p + 12);
    };
    auto loadB = [&](int k0) {
        const u16* ph = &Bgh[(size_t)(col0 + srow) * kD + k0 + skq];
        bRh[0] = *(const bf16x8*)ph; bRh[1] = *(const bf16x8*)(ph + 8);
    };
    auto writeAB = [&]() {
        const int c0 = skq >> 3, sw = srow & 3;
        bf16x8 h0, h1, l0, l1;
        const float* af = (const float*)aR;
        #pragma unroll
        for (int q = 0; q < 8; ++q) {
            u16 hh, ll;
            splitf(af[q], hh, ll);     h0[q] = (short)hh; l0[q] = (short)ll;
            splitf(af[8 + q], hh, ll); h1[q] = (short)hh; l1[q] = (short)ll;
        }
        *(bf16x8*)&Ash[srow * 32 + (((c0    ) ^ sw) << 3)] = h0;
        *(bf16x8*)&Ash[srow * 32 + (((c0 + 1) ^ sw) << 3)] = h1;
        *(bf16x8*)&Asl[srow * 32 + (((c0    ) ^ sw) << 3)] = l0;
        *(bf16x8*)&Asl[srow * 32 + (((c0 + 1) ^ sw) << 3)] = l1;
        *(bf16x8*)&Bsh[srow * 32 + (((c0    ) ^ sw) << 3)] = bRh[0];
        *(bf16x8*)&Bsh[srow * 32 + (((c0 + 1) ^ sw) << 3)] = bRh[1];
    };

    loadA(0); loadB(0);
    for (int k0 = 0; k0 < kD; k0 += 32) {
        __syncthreads();
        writeAB();
        __syncthreads();
        if (k0 + 32 < kD) { loadA(k0 + 32); loadB(k0 + 32); }

        bf16x8 fAh[4], fAl[4], fBh[4];
        #pragma unroll
        for (int m = 0; m < 4; ++m) {
            int ar = wrow * 64 + m * 16 + s;
            int off = ar * 32 + ((g ^ (ar & 3)) << 3);
            fAh[m] = *(const bf16x8*)&Ash[off];
            fAl[m] = *(const bf16x8*)&Asl[off];
        }
        #pragma unroll
        for (int n = 0; n < 4; ++n) {
            int bc = wcol * 64 + n * 16 + s;
            int off = bc * 32 + ((g ^ (bc & 3)) << 3);
            fBh[n] = *(const bf16x8*)&Bsh[off];
        }
        #pragma unroll
        for (int m = 0; m < 4; ++m)
            #pragma unroll
            for (int n = 0; n < 4; ++n) {
                acc[m][n] = MFMA(fAh[m], fBh[n], acc[m][n]);
                acc[m][n] = MFMA(fAl[m], fBh[n], acc[m][n]);
            }
    }

    #pragma unroll
    for (int n = 0; n < 4; ++n) {
        const int colg = col0 + wcol * 64 + n * 16 + s;
        const float bv = bias[colg];
        #pragma unroll
        for (int m = 0; m < 4; ++m) {
            const int rowg = row0 + wrow * 64 + m * 16 + (g << 2);
            if (z == 2) {
                const int b = rowg >> 11, i = rowg & (kL - 1);
                const int h = colg >> 6, d = colg & 63;
                ushort4 o4;
                o4.x = f2bf(acc[m][n][0] + bv);
                o4.y = f2bf(acc[m][n][1] + bv);
                o4.z = f2bf(acc[m][n][2] + bv);
                o4.w = f2bf(acc[m][n][3] + bv);
                *(ushort4*)&Yh[(((size_t)b * kH + h) * kDK + d) * kL + i] = o4;
            } else {
                #pragma unroll
                for (int r = 0; r < 4; ++r) {
                    float val = (acc[m][n][r] + bv) * scale;
                    const int rg = rowg + r;
                    const int b = rg >> 11, i = rg & (kL - 1);
                    const int h = colg >> 6, d = colg & 63;
                    Yh[(((size_t)b * kH + h) * kL + i) * kDK + d] = f2bf(val);
                }
            }
        }
    }
}

// ---------------------------------------------------------------------------
// K4: output GEMM  out = concat @ Wo^T + bo  (3-term, fp32 out)
//  R12-proven reg-staged structure + XCD chunked block swizzle.
// ---------------------------------------------------------------------------
__global__ __launch_bounds__(256) void out_gemm(
    const u16* __restrict__ Agh, const u16* __restrict__ Agl,
    const u16* __restrict__ Bgh, const u16* __restrict__ Bgl,
    const float* __restrict__ bias, float* __restrict__ Yf)
{
    __shared__ __align__(16) u16 Ash[128 * 32], Asl[128 * 32];
    __shared__ __align__(16) u16 Bsh[128 * 32], Bsl[128 * 32];

    const int tid = threadIdx.x;
    const int pb = blockIdx.x + 64 * blockIdx.y;
    const int lb = (pb & 7) * 64 + (pb >> 3);
    const int row0 = (lb & 63) * 128, col0 = (lb >> 6) * 128;
    const int w = tid >> 6, lane = tid & 63;
    const int s = lane & 15, g = lane >> 4;
    const int wrow = w >> 1, wcol = w & 1;
    const int srow = tid >> 1;
    const int skq  = (tid & 1) * 16;

    const f32x4 fz = {0.f, 0.f, 0.f, 0.f};
    f32x4 acc[4][4];
    #pragma unroll
    for (int m = 0; m < 4; ++m)
        #pragma unroll
        for (int n = 0; n < 4; ++n) acc[m][n] = fz;

    bf16x8 aRh[2], aRl[2], bRh[2], bRl[2];
    auto loadA = [&](int k0) {
        const u16* ph = &Agh[(size_t)(row0 + srow) * kD + k0 + skq];
        const u16* pl = &Agl[(size_t)(row0 + srow) * kD + k0 + skq];
        aRh[0] = *(const bf16x8*)ph; aRh[1] = *(const bf16x8*)(ph + 8);
        aRl[0] = *(const bf16x8*)pl; aRl[1] = *(const bf16x8*)(pl + 8);
    };
    auto loadB = [&](int k0) {
        const u16* ph = &Bgh[(size_t)(col0 + srow) * kD + k0 + skq];
        const u16* pl = &Bgl[(size_t)(col0 + srow) * kD + k0 + skq];
        bRh[0] = *(const bf16x8*)ph; bRh[1] = *(const bf16x8*)(ph + 8);
        bRl[0] = *(const bf16x8*)pl; bRl[1] = *(const bf16x8*)(pl + 8);
    };
    auto writeAB = [&]() {
        const int c0 = skq >> 3, sw = srow & 3;
        *(bf16x8*)&Ash[srow * 32 + (((c0    ) ^ sw) << 3)] = aRh[0];
        *(bf16x8*)&Ash[srow * 32 + (((c0 + 1) ^ sw) << 3)] = aRh[1];
        *(bf16x8*)&Asl[srow * 32 + (((c0    ) ^ sw) << 3)] = aRl[0];
        *(bf16x8*)&Asl[srow * 32 + (((c0 + 1) ^ sw) << 3)] = aRl[1];
        *(bf16x8*)&Bsh[srow * 32 + (((c0    ) ^ sw) << 3)] = bRh[0];
        *(bf16x8*)&Bsh[srow * 32 + (((c0 + 1) ^ sw) << 3)] = bRh[1];
        *(bf16x8*)&Bsl[srow * 32 + (((c0    ) ^ sw) << 3)] = bRl[0];
        *(bf16x8*)&Bsl[srow * 32 + (((c0 + 1) ^ sw) << 3)] = bRl[1];
    };

    loadA(0); loadB(0);
    for (int k0 = 0; k0 < kD; k0 += 32) {
        __syncthreads();
        writeAB();
        __syncthreads();
        if (k0 + 32 < kD) { loadA(k0 + 32); loadB(k0 + 32); }

        bf16x8 fAh[4], fAl[4], fBh[4], fBl[4];
        #pragma unroll
        for (int m = 0; m < 4; ++m) {
            int ar = wrow * 64 + m * 16 + s;
            int off = ar * 32 + ((g ^ (ar & 3)) << 3);
            fAh[m] = *(const bf16x8*)&Ash[off];
            fAl[m] = *(const bf16x8*)&Asl[off];
        }
        #pragma unroll
        for (int n = 0; n < 4; ++n) {
            int bc = wcol * 64 + n * 16 + s;
            int off = bc * 32 + ((g ^ (bc & 3)) << 3);
            fBh[n] = *(const bf16x8*)&Bsh[off];
            fBl[n] = *(const bf16x8*)&Bsl[off];
        }
        #pragma unroll
        for (int m = 0; m < 4; ++m)
            #pragma unroll
            for (int n = 0; n < 4; ++n) {
                acc[m][n] = MFMA(fAh[m], fBh[n], acc[m][n]);
                acc[m][n] = MFMA(fAl[m], fBh[n], acc[m][n]);
                acc[m][n] = MFMA(fAh[m], fBl[n], acc[m][n]);
            }
    }

    #pragma unroll
    for (int n = 0; n < 4; ++n) {
        const int colg = col0 + wcol * 64 + n * 16 + s;
        const float bv = bias[colg];
        #pragma unroll
        for (int m = 0; m < 4; ++m) {
            const int rowg = row0 + wrow * 64 + m * 16 + (g << 2);
            #pragma unroll
            for (int r = 0; r < 4; ++r)
                Yf[(size_t)(rowg + r) * kD + colg] = acc[m][n][r] + bv;
        }
    }
}

// ---------------------------------------------------------------------------
// K3: flash attention (R14, verified at 219 µs): swapped QK, dbuf K/V/W gll,
//     bias software pipeline, ones-MFMA l, XCD bijective block swizzle.
// ---------------------------------------------------------------------------
__global__ __launch_bounds__(256, 2) void attn3(
    const u16* __restrict__ Qh,
    const u16* __restrict__ Kg, const u16* __restrict__ VT,
    const u16* __restrict__ Wr,
    u16* __restrict__ Ch, u16* __restrict__ Cl)
{
    __shared__ __align__(16) u16 Ksh[2][64 * 64];   // [j][d] swizzled     16 KB
    __shared__ __align__(16) u16 Vsh[2][64 * 64];   // V^T [d][j] swizzled 16 KB
    __shared__ __align__(16) u16 Wsh[2][64 * 64];   // [u_loc][d] swizzled 16 KB
    __shared__ __align__(16) u16 Ps[4][16 * 64];    // per-wave P[i][j]     8 KB
    __shared__ __align__(16) u16 Tb[64 * 132];      // bias [il][key]    16.5 KB

    const int tid = threadIdx.x;
    const int w = tid >> 6, lane = tid & 63;
    const int s = lane & 15, g = lane >> 4;
    const int pb = blockIdx.x + 32 * blockIdx.y;    // physical block id
    const int lb = (pb & 7) * 256 + (pb >> 3);      // bijective XCD swizzle
    const int bh = lb >> 5, i0 = (lb & 31) * 64;
    const int b = bh >> 4, h = bh & 15;

    const int srow = tid >> 3;      // staging: dest row (tid>>3)+32*it
    const int sc = tid & 7;         // dest 16B chunk

    auto stageK = [&](int buf, int t) {
        const u16* base = Kg + ((size_t)bh * kL + (size_t)t * 64) * kDK;
        #pragma unroll
        for (int it = 0; it < 2; ++it) {
            int r = srow + it * 32;
            gll16(base + r * 64 + ((sc ^ (r & 7)) << 3), &Ksh[buf][it * 2048 + w * 512]);
        }
    };
    auto stageV = [&](int buf, int t) {
        #pragma unroll
        for (int it = 0; it < 2; ++it) {
            int d = srow + it * 32;
            const u16* src = VT + ((size_t)bh * kDK + d) * kL + t * 64 + ((sc ^ (d & 7)) << 3);
            gll16(src, &Vsh[buf][it * 2048 + w * 512]);
        }
    };
    auto stageW = [&](int buf, int c) {
        #pragma unroll
        for (int it = 0; it < 2; ++it) {
            int r = srow + it * 32;
            long row = (long)i0 + 64L * c + r;
            if (row > kWrelMax) row = kWrelMax;
            gll16(Wr + row * 64 + ((sc ^ (r & 7)) << 3), &Wsh[buf][it * 2048 + w * 512]);
        }
    };

    // ---- hoisted LDS fragment offsets ----
    int foff[4][2];                 // K/V/W fragment reads
    #pragma unroll
    for (int n = 0; n < 4; ++n)
        #pragma unroll
        for (int ks = 0; ks < 2; ++ks) {
            int row = n * 16 + s;
            foff[n][ks] = row * 64 + (((ks * 4 + g) ^ (row & 7)) << 3);
        }
    int prd[2];                     // Ps A-fragment reads (rows i=s)
    #pragma unroll
    for (int ks = 0; ks < 2; ++ks)
        prd[ks] = s * 64 + (((ks * 4 + g) ^ (s & 7)) << 3);
    int pwr[4];                     // Ps b64 writes: row i=s, j=16jn+4g..+3
    #pragma unroll
    for (int jn = 0; jn < 4; ++jn) {
        int c = 2 * jn + (g >> 1);
        pwr[jn] = s * 64 + ((c ^ (s & 7)) << 3) + (g & 1) * 4;
    }

    // Q fragments (pre-scaled by 0.125*log2e in projection)
    const size_t qbase = ((size_t)bh * kL + i0 + w * 16 + s) * kDK + g * 8;
    bf16x8 qh[2];
    qh[0] = *(const bf16x8*)&Qh[qbase];
    qh[1] = *(const bf16x8*)&Qh[qbase + 32];

    const f32x4 fz = {0.f, 0.f, 0.f, 0.f};
    const int ilS = w * 16 + s;       // Tb read row
    const int ilw = w * 16 + g * 4;   // Tb write base row

    // T-gemm: T[il][u] stored at Tb[il][key=(u_loc-il)&127]; rows wave-private
    auto computeT = [&](int c, int buf) {
        f32x4 tacc[4];
        #pragma unroll
        for (int un = 0; un < 4; ++un) {
            bf16x8 wf0 = *(const bf16x8*)&Wsh[buf][foff[un][0]];
            bf16x8 wf1 = *(const bf16x8*)&Wsh[buf][foff[un][1]];
            tacc[un] = MFMA(qh[0], wf0, fz);
            tacc[un] = MFMA(qh[1], wf1, tacc[un]);
        }
        const int cb = c * 64 - w * 16 + s - g * 4;
        #pragma unroll
        for (int un = 0; un < 4; ++un)
            #pragma unroll
            for (int r = 0; r < 4; ++r) {
                int key = (cb + un * 16 - r) & 127;
                Tb[(ilw + r) * 132 + key] =
                    (u16)(__float_as_uint(tacc[un][r]) >> 16);
            }
    };

    f32x4 sacc[4];
    auto loadBias = [&](int t) {
        #pragma unroll
        for (int jn = 0; jn < 4; ++jn) {
            int kb = (t * 64 + jn * 16 + g * 4) & 127;   // 4-aligned
            uint2 tw = *(const uint2*)&Tb[ilS * 132 + kb];
            sacc[jn][0] = __uint_as_float(tw.x << 16);
            sacc[jn][1] = __uint_as_float(tw.x & 0xFFFF0000u);
            sacc[jn][2] = __uint_as_float(tw.y << 16);
            sacc[jn][3] = __uint_as_float(tw.y & 0xFFFF0000u);
        }
    };

    bf16x8 ones;
    #pragma unroll
    for (int q = 0; q < 8; ++q) ones[q] = (short)0x3F80;

    // prologue
    stageK(0, 0); stageV(0, 0); stageW(0, 0); stageW(1, 1);
    __syncthreads();                        // W0,W1,K0,V0 landed
    computeT(0, 0); computeT(1, 1);
    loadBias(0);                            // own-wave rows, program-ordered
    __syncthreads();                        // all waves done reading Wsh[0/1]
    stageW(0, 2);                           // chunk 2 into buf 0
    __syncthreads();                        // chunk-2 W landed

    f32x4 oacc[4] = {fz, fz, fz, fz};
    f32x4 lacc = fz;

    for (int t = 0; t < 32; ++t) {
        const int cur = t & 1, nxt = cur ^ 1;
        if (t < 31) { stageK(nxt, t + 1); stageV(nxt, t + 1); }
        if (t < 30) stageW(nxt, t + 3);     // buf (t+3)&1 == nxt
        if (t < 31) computeT(t + 2, cur);   // chunk t+2 staged at t-1 into buf t&1

        // ---- S^T = K Q^T + bias (sacc preloaded last tile) ----
        __builtin_amdgcn_s_setprio(1);
        #pragma unroll
        for (int jn = 0; jn < 4; ++jn)
            #pragma unroll
            for (int ks = 0; ks < 2; ++ks) {
                bf16x8 kf = *(const bf16x8*)&Ksh[cur][foff[jn][ks]];
                sacc[jn] = MFMA(kf, qh[ks], sacc[jn]);
            }
        __builtin_amdgcn_s_setprio(0);

        // ---- p = exp2(s); trunc-pack pairs; one b64 write per jn ----
        #pragma unroll
        for (int jn = 0; jn < 4; ++jn) {
            u32 a0 = __float_as_uint(fexp2(sacc[jn][0])) & 0xFFFF0000u;
            u32 a1 = __float_as_uint(fexp2(sacc[jn][1])) & 0xFFFF0000u;
            u32 a2 = __float_as_uint(fexp2(sacc[jn][2])) & 0xFFFF0000u;
            u32 a3 = __float_as_uint(fexp2(sacc[jn][3])) & 0xFFFF0000u;
            uint2 pw;
            pw.x = a1 | (a0 >> 16);   // lo u16 = p0 (col j), hi u16 = p1
            pw.y = a3 | (a2 >> 16);
            *(uint2*)&Ps[w][pwr[jn]] = pw;
        }

        // ---- prefetch next tile's bias into sacc (dead after exp2) ----
        if (t < 31) loadBias(t + 1);

        // ---- O += P V;  l += P * ones ----
        __builtin_amdgcn_s_setprio(1);
        #pragma unroll
        for (int ks = 0; ks < 2; ++ks) {
            bf16x8 pf = *(const bf16x8*)&Ps[w][prd[ks]];
            lacc = MFMA(pf, ones, lacc);
            #pragma unroll
            for (int dn = 0; dn < 4; ++dn) {
                bf16x8 vf = *(const bf16x8*)&Vsh[cur][foff[dn][ks]];
                oacc[dn] = MFMA(pf, vf, oacc[dn]);
            }
        }
        __builtin_amdgcn_s_setprio(0);
        __syncthreads();   // drains gll issued this tile; releases cur bufs
    }

    // ---- epilogue: lacc[r] is already l[i = w*16 + g*4 + r] ----
    float invr[4];
    #pragma unroll
    for (int r = 0; r < 4; ++r) invr[r] = 1.0f / lacc[r];

    #pragma unroll
    for (int dn = 0; dn < 4; ++dn)
        #pragma unroll
        for (int r = 0; r < 4; ++r) {
            const int ig = i0 + w * 16 + g * 4 + r;
            float val = oacc[dn][r] * invr[r];
            u16 hh, ll; splitf(val, hh, ll);
            size_t o = ((size_t)(b * kL + ig)) * kD + h * kDK + dn * 16 + s;
            Ch[o] = hh; Cl[o] = ll;
        }
}

// ---------------------------------------------------------------------------
extern "C" void kernel_launch(void* const* d_in, const int* in_sizes, int n_in,
                              void* d_out, int out_size, void* d_ws, size_t ws_size,
                              hipStream_t stream) {
    const float* q    = (const float*)d_in[0];
    const float* k    = (const float*)d_in[1];
    const float* v    = (const float*)d_in[2];
    const float* Wq   = (const float*)d_in[3];
    const float* bq   = (const float*)d_in[4];
    const float* Wk   = (const float*)d_in[5];
    const float* bk   = (const float*)d_in[6];
    const float* Wv   = (const float*)d_in[7];
    const float* bv   = (const float*)d_in[8];
    const float* Wo   = (const float*)d_in[9];
    const float* bo   = (const float*)d_in[10];
    const float* wrel = (const float*)d_in[11];
    float* out = (float*)d_out;

    u16* p = (u16*)d_ws;
    const size_t nW = (size_t)kD * kD;
    const size_t nR = (size_t)(2 * kL - 1) * kDK;
    const size_t nT = (size_t)kB * kL * kD;
    u16* wqh = p; p += nW;  u16* wql = p; p += nW;
    u16* wkh = p; p += nW;  u16* wkl = p; p += nW;
    u16* wvh = p; p += nW;  u16* wvl = p; p += nW;
    u16* woh = p; p += nW;  u16* wol = p; p += nW;
    u16* wrh = p; p += nR;  u16* wrl = p; p += nR;
    u16* qhh = p; p += nT;
    u16* khh = p; p += nT;
    u16* vT  = p; p += nT;
    u16* cch = p; p += nT;  u16* ccl = p; p += nT;

    // K1: weight splits (4 fused) + w_rel split
    hipLaunchKernelGGL(split4x4_kernel, dim3(1024, 4), dim3(256), 0, stream,
                       Wq, Wk, Wv, Wo, wqh, wkh, wvh, woh, wql, wkl, wvl, wol,
                       (int)(nW / 4));
    hipLaunchKernelGGL(split4_kernel, dim3(256), dim3(256), 0, stream,
                       wrel, wrh, wrl, (int)(nR / 4));

    dim3 blk(256);
    // K2: merged Q/K/V projections
    hipLaunchKernelGGL(proj3, dim3(64, 8, 3), blk, 0, stream,
                       q, k, v, wqh, wkh, wvh, bq, bk, bv, qhh, khh, vT);

    // K3: attention
    hipLaunchKernelGGL(attn3, dim3(kL / 64, kB * kH), blk, 0, stream,
                       qhh, khh, vT, wrh, cch, ccl);

    // K4: output projection
    hipLaunchKernelGGL(out_gemm, dim3(64, 8), blk, 0, stream,
                       cch, ccl, woh, wol, bo, out);
}

// Round 16
// 370.444 us; speedup vs baseline: 1.1361x; 1.0628x over previous
//
#include <hip/hip_runtime.h>

typedef __attribute__((ext_vector_type(8))) short bf16x8;
typedef __attribute__((ext_vector_type(4))) float f32x4;
typedef unsigned short u16;
typedef unsigned int u32;

constexpr int kB = 4, kL = 2048, kD = 1024, kH = 16, kDK = 64;
constexpr int kR = kB * kL;
constexpr long kWrelMax = 2 * kL - 2;   // 4094 = last valid w_rel row
constexpr float kQScale = 0.125f * 1.44269504088896f;  // 1/sqrt(dk) * log2(e)

__device__ inline float fexp2(float x) { return __builtin_amdgcn_exp2f(x); }

__device__ inline u16 f2bf(float x) {
    union { float f; u32 u; } v; v.f = x;
    u32 r = v.u + 0x7FFFu + ((v.u >> 16) & 1u);   // RNE
    return (u16)(r >> 16);
}
// trunc split: hi = trunc_bf16(x), lo = trunc_bf16(x - hi)
__device__ inline void splitf(float x, u16& hi, u16& lo) {
    union { float f; u32 u; } v; v.f = x;
    u32 hu = v.u & 0xFFFF0000u;
    hi = (u16)(hu >> 16);
    union { u32 u; float f; } hf; hf.u = hu;
    union { float f; u32 u; } l; l.f = x - hf.f;
    lo = (u16)(l.u >> 16);
}
__device__ inline f32x4 MFMA(bf16x8 a, bf16x8 b, f32x4 c) {
    return __builtin_amdgcn_mfma_f32_16x16x32_bf16(a, b, c, 0, 0, 0);
}
// async global->LDS, 16B per lane; LDS dest = wave-uniform base + lane*16
__device__ __forceinline__ void gll16(const u16* g, u16* l) {
    __builtin_amdgcn_global_load_lds(
        (const __attribute__((address_space(1))) u32*)g,
        (__attribute__((address_space(3))) u32*)l, 16, 0, 0);
}

// ---------------------------------------------------------------------------
// K1: fp32 -> bf16 hi/lo split; 4 tensors in one launch (blockIdx.y selects)
// ---------------------------------------------------------------------------
__global__ void split4x4_kernel(const float* __restrict__ i0, const float* __restrict__ i1,
                                const float* __restrict__ i2, const float* __restrict__ i3,
                                u16* __restrict__ h0, u16* __restrict__ h1,
                                u16* __restrict__ h2, u16* __restrict__ h3,
                                u16* __restrict__ l0, u16* __restrict__ l1,
                                u16* __restrict__ l2, u16* __restrict__ l3, int n4) {
    int idx = blockIdx.x * blockDim.x + threadIdx.x;
    if (idx >= n4) return;
    const float* in = blockIdx.y == 0 ? i0 : blockIdx.y == 1 ? i1 : blockIdx.y == 2 ? i2 : i3;
    u16* hi = blockIdx.y == 0 ? h0 : blockIdx.y == 1 ? h1 : blockIdx.y == 2 ? h2 : h3;
    u16* lo = blockIdx.y == 0 ? l0 : blockIdx.y == 1 ? l1 : blockIdx.y == 2 ? l2 : l3;
    float4 x = reinterpret_cast<const float4*>(in)[idx];
    ushort4 h, l;
    splitf(x.x, h.x, l.x); splitf(x.y, h.y, l.y);
    splitf(x.z, h.z, l.z); splitf(x.w, h.w, l.w);
    reinterpret_cast<ushort4*>(hi)[idx] = h;
    reinterpret_cast<ushort4*>(lo)[idx] = l;
}
__global__ void split4_kernel(const float* __restrict__ in,
                              u16* __restrict__ hi, u16* __restrict__ lo, int n4) {
    int idx = blockIdx.x * blockDim.x + threadIdx.x;
    if (idx >= n4) return;
    float4 x = reinterpret_cast<const float4*>(in)[idx];
    ushort4 h, l;
    splitf(x.x, h.x, l.x); splitf(x.y, h.y, l.y);
    splitf(x.z, h.z, l.z); splitf(x.w, h.w, l.w);
    reinterpret_cast<ushort4*>(hi)[idx] = h;
    reinterpret_cast<ushort4*>(lo)[idx] = l;
}

// ---------------------------------------------------------------------------
// K2: merged Q/K/V projection GEMM (blockIdx.z selects). 2-term exact-A.
//  R12-proven reg-staged structure (2 barriers/K-step, loads 1 iter ahead).
// ---------------------------------------------------------------------------
__global__ __launch_bounds__(256) void proj3(
    const float* __restrict__ Aq, const float* __restrict__ Ak, const float* __restrict__ Av,
    const u16* __restrict__ Bqh, const u16* __restrict__ Bkh, const u16* __restrict__ Bvh,
    const float* __restrict__ bq, const float* __restrict__ bk, const float* __restrict__ bv,
    u16* __restrict__ Yq, u16* __restrict__ Yk, u16* __restrict__ Yv)
{
    __shared__ __align__(16) u16 Ash[128 * 32], Asl[128 * 32];
    __shared__ __align__(16) u16 Bsh[128 * 32];

    const int z = blockIdx.z;
    const float* Af32 = z == 0 ? Aq : z == 1 ? Ak : Av;
    const u16* Bgh    = z == 0 ? Bqh : z == 1 ? Bkh : Bvh;
    const float* bias = z == 0 ? bq : z == 1 ? bk : bv;
    u16* Yh           = z == 0 ? Yq : z == 1 ? Yk : Yv;
    const float scale = z == 0 ? kQScale : 1.0f;

    const int tid = threadIdx.x;
    const int row0 = blockIdx.x * 128, col0 = blockIdx.y * 128;
    const int w = tid >> 6, lane = tid & 63;
    const int s = lane & 15, g = lane >> 4;
    const int wrow = w >> 1, wcol = w & 1;
    const int srow = tid >> 1;
    const int skq  = (tid & 1) * 16;

    const f32x4 fz = {0.f, 0.f, 0.f, 0.f};
    f32x4 acc[4][4];
    #pragma unroll
    for (int m = 0; m < 4; ++m)
        #pragma unroll
        for (int n = 0; n < 4; ++n) acc[m][n] = fz;

    float4 aR[4];
    bf16x8 bRh[2];

    auto loadA = [&](int k0) {
        const float* p = &Af32[(size_t)(row0 + srow) * kD + k0 + skq];
        aR[0] = *(const float4*)(p);
        aR[1] = *(const float4*)(p + 4);
        aR[2] = *(const float4*)(p + 8);
        aR[3] = *(const float4*)(p + 12);
    };
    auto loadB = [&](int k0) {
        const u16* ph = &Bgh[(size_t)(col0 + srow) * kD + k0 + skq];
        bRh[0] = *(const bf16x8*)ph; bRh[1] = *(const bf16x8*)(ph + 8);
    };
    auto writeAB = [&]() {
        const int c0 = skq >> 3, sw = srow & 3;
        bf16x8 h0, h1, l0, l1;
        const float* af = (const float*)aR;
        #pragma unroll
        for (int q = 0; q < 8; ++q) {
            u16 hh, ll;
            splitf(af[q], hh, ll);     h0[q] = (short)hh; l0[q] = (short)ll;
            splitf(af[8 + q], hh, ll); h1[q] = (short)hh; l1[q] = (short)ll;
        }
        *(bf16x8*)&Ash[srow * 32 + (((c0    ) ^ sw) << 3)] = h0;
        *(bf16x8*)&Ash[srow * 32 + (((c0 + 1) ^ sw) << 3)] = h1;
        *(bf16x8*)&Asl[srow * 32 + (((c0    ) ^ sw) << 3)] = l0;
        *(bf16x8*)&Asl[srow * 32 + (((c0 + 1) ^ sw) << 3)] = l1;
        *(bf16x8*)&Bsh[srow * 32 + (((c0    ) ^ sw) << 3)] = bRh[0];
        *(bf16x8*)&Bsh[srow * 32 + (((c0 + 1) ^ sw) << 3)] = bRh[1];
    };

    loadA(0); loadB(0);
    for (int k0 = 0; k0 < kD; k0 += 32) {
        __syncthreads();
        writeAB();
        __syncthreads();
        if (k0 + 32 < kD) { loadA(k0 + 32); loadB(k0 + 32); }

        bf16x8 fAh[4], fAl[4], fBh[4];
        #pragma unroll
        for (int m = 0; m < 4; ++m) {
            int ar = wrow * 64 + m * 16 + s;
            int off = ar * 32 + ((g ^ (ar & 3)) << 3);
            fAh[m] = *(const bf16x8*)&Ash[off];
            fAl[m] = *(const bf16x8*)&Asl[off];
        }
        #pragma unroll
        for (int n = 0; n < 4; ++n) {
            int bc = wcol * 64 + n * 16 + s;
            int off = bc * 32 + ((g ^ (bc & 3)) << 3);
            fBh[n] = *(const bf16x8*)&Bsh[off];
        }
        #pragma unroll
        for (int m = 0; m < 4; ++m)
            #pragma unroll
            for (int n = 0; n < 4; ++n) {
                acc[m][n] = MFMA(fAh[m], fBh[n], acc[m][n]);
                acc[m][n] = MFMA(fAl[m], fBh[n], acc[m][n]);
            }
    }

    #pragma unroll
    for (int n = 0; n < 4; ++n) {
        const int colg = col0 + wcol * 64 + n * 16 + s;
        const float bv = bias[colg];
        #pragma unroll
        for (int m = 0; m < 4; ++m) {
            const int rowg = row0 + wrow * 64 + m * 16 + (g << 2);
            if (z == 2) {
                const int b = rowg >> 11, i = rowg & (kL - 1);
                const int h = colg >> 6, d = colg & 63;
                ushort4 o4;
                o4.x = f2bf(acc[m][n][0] + bv);
                o4.y = f2bf(acc[m][n][1] + bv);
                o4.z = f2bf(acc[m][n][2] + bv);
                o4.w = f2bf(acc[m][n][3] + bv);
                *(ushort4*)&Yh[(((size_t)b * kH + h) * kDK + d) * kL + i] = o4;
            } else {
                #pragma unroll
                for (int r = 0; r < 4; ++r) {
                    float val = (acc[m][n][r] + bv) * scale;
                    const int rg = rowg + r;
                    const int b = rg >> 11, i = rg & (kL - 1);
                    const int h = colg >> 6, d = colg & 63;
                    Yh[(((size_t)b * kH + h) * kL + i) * kDK + d] = f2bf(val);
                }
            }
        }
    }
}

// ---------------------------------------------------------------------------
// K4: output GEMM  out = concat @ Wo^T + bo  (3-term, fp32 out)
//  R12-proven reg-staged structure.
// ---------------------------------------------------------------------------
__global__ __launch_bounds__(256) void out_gemm(
    const u16* __restrict__ Agh, const u16* __restrict__ Agl,
    const u16* __restrict__ Bgh, const u16* __restrict__ Bgl,
    const float* __restrict__ bias, float* __restrict__ Yf)
{
    __shared__ __align__(16) u16 Ash[128 * 32], Asl[128 * 32];
    __shared__ __align__(16) u16 Bsh[128 * 32], Bsl[128 * 32];

    const int tid = threadIdx.x;
    const int row0 = blockIdx.x * 128, col0 = blockIdx.y * 128;
    const int w = tid >> 6, lane = tid & 63;
    const int s = lane & 15, g = lane >> 4;
    const int wrow = w >> 1, wcol = w & 1;
    const int srow = tid >> 1;
    const int skq  = (tid & 1) * 16;

    const f32x4 fz = {0.f, 0.f, 0.f, 0.f};
    f32x4 acc[4][4];
    #pragma unroll
    for (int m = 0; m < 4; ++m)
        #pragma unroll
        for (int n = 0; n < 4; ++n) acc[m][n] = fz;

    bf16x8 aRh[2], aRl[2], bRh[2], bRl[2];
    auto loadA = [&](int k0) {
        const u16* ph = &Agh[(size_t)(row0 + srow) * kD + k0 + skq];
        const u16* pl = &Agl[(size_t)(row0 + srow) * kD + k0 + skq];
        aRh[0] = *(const bf16x8*)ph; aRh[1] = *(const bf16x8*)(ph + 8);
        aRl[0] = *(const bf16x8*)pl; aRl[1] = *(const bf16x8*)(pl + 8);
    };
    auto loadB = [&](int k0) {
        const u16* ph = &Bgh[(size_t)(col0 + srow) * kD + k0 + skq];
        const u16* pl = &Bgl[(size_t)(col0 + srow) * kD + k0 + skq];
        bRh[0] = *(const bf16x8*)ph; bRh[1] = *(const bf16x8*)(ph + 8);
        bRl[0] = *(const bf16x8*)pl; bRl[1] = *(const bf16x8*)(pl + 8);
    };
    auto writeAB = [&]() {
        const int c0 = skq >> 3, sw = srow & 3;
        *(bf16x8*)&Ash[srow * 32 + (((c0    ) ^ sw) << 3)] = aRh[0];
        *(bf16x8*)&Ash[srow * 32 + (((c0 + 1) ^ sw) << 3)] = aRh[1];
        *(bf16x8*)&Asl[srow * 32 + (((c0    ) ^ sw) << 3)] = aRl[0];
        *(bf16x8*)&Asl[srow * 32 + (((c0 + 1) ^ sw) << 3)] = aRl[1];
        *(bf16x8*)&Bsh[srow * 32 + (((c0    ) ^ sw) << 3)] = bRh[0];
        *(bf16x8*)&Bsh[srow * 32 + (((c0 + 1) ^ sw) << 3)] = bRh[1];
        *(bf16x8*)&Bsl[srow * 32 + (((c0    ) ^ sw) << 3)] = bRl[0];
        *(bf16x8*)&Bsl[srow * 32 + (((c0 + 1) ^ sw) << 3)] = bRl[1];
    };

    loadA(0); loadB(0);
    for (int k0 = 0; k0 < kD; k0 += 32) {
        __syncthreads();
        writeAB();
        __syncthreads();
        if (k0 + 32 < kD) { loadA(k0 + 32); loadB(k0 + 32); }

        bf16x8 fAh[4], fAl[4], fBh[4], fBl[4];
        #pragma unroll
        for (int m = 0; m < 4; ++m) {
            int ar = wrow * 64 + m * 16 + s;
            int off = ar * 32 + ((g ^ (ar & 3)) << 3);
            fAh[m] = *(const bf16x8*)&Ash[off];
            fAl[m] = *(const bf16x8*)&Asl[off];
        }
        #pragma unroll
        for (int n = 0; n < 4; ++n) {
            int bc = wcol * 64 + n * 16 + s;
            int off = bc * 32 + ((g ^ (bc & 3)) << 3);
            fBh[n] = *(const bf16x8*)&Bsh[off];
            fBl[n] = *(const bf16x8*)&Bsl[off];
        }
        #pragma unroll
        for (int m = 0; m < 4; ++m)
            #pragma unroll
            for (int n = 0; n < 4; ++n) {
                acc[m][n] = MFMA(fAh[m], fBh[n], acc[m][n]);
                acc[m][n] = MFMA(fAl[m], fBh[n], acc[m][n]);
                acc[m][n] = MFMA(fAh[m], fBl[n], acc[m][n]);
            }
    }

    #pragma unroll
    for (int n = 0; n < 4; ++n) {
        const int colg = col0 + wcol * 64 + n * 16 + s;
        const float bv = bias[colg];
        #pragma unroll
        for (int m = 0; m < 4; ++m) {
            const int rowg = row0 + wrow * 64 + m * 16 + (g << 2);
            #pragma unroll
            for (int r = 0; r < 4; ++r)
                Yf[(size_t)(rowg + r) * kD + colg] = acc[m][n][r] + bv;
        }
    }
}

// ---------------------------------------------------------------------------
// K3: flash attention (R14/R15, verified at 219 µs): swapped QK, dbuf K/V/W
//     gll, bias software pipeline, ones-MFMA l, XCD bijective block swizzle.
// ---------------------------------------------------------------------------
__global__ __launch_bounds__(256, 2) void attn3(
    const u16* __restrict__ Qh,
    const u16* __restrict__ Kg, const u16* __restrict__ VT,
    const u16* __restrict__ Wr,
    u16* __restrict__ Ch, u16* __restrict__ Cl)
{
    __shared__ __align__(16) u16 Ksh[2][64 * 64];   // [j][d] swizzled     16 KB
    __shared__ __align__(16) u16 Vsh[2][64 * 64];   // V^T [d][j] swizzled 16 KB
    __shared__ __align__(16) u16 Wsh[2][64 * 64];   // [u_loc][d] swizzled 16 KB
    __shared__ __align__(16) u16 Ps[4][16 * 64];    // per-wave P[i][j]     8 KB
    __shared__ __align__(16) u16 Tb[64 * 132];      // bias [il][key]    16.5 KB

    const int tid = threadIdx.x;
    const int w = tid >> 6, lane = tid & 63;
    const int s = lane & 15, g = lane >> 4;
    const int pb = blockIdx.x + 32 * blockIdx.y;    // physical block id
    const int lb = (pb & 7) * 256 + (pb >> 3);      // bijective XCD swizzle
    const int bh = lb >> 5, i0 = (lb & 31) * 64;
    const int b = bh >> 4, h = bh & 15;

    const int srow = tid >> 3;      // staging: dest row (tid>>3)+32*it
    const int sc = tid & 7;         // dest 16B chunk

    auto stageK = [&](int buf, int t) {
        const u16* base = Kg + ((size_t)bh * kL + (size_t)t * 64) * kDK;
        #pragma unroll
        for (int it = 0; it < 2; ++it) {
            int r = srow + it * 32;
            gll16(base + r * 64 + ((sc ^ (r & 7)) << 3), &Ksh[buf][it * 2048 + w * 512]);
        }
    };
    auto stageV = [&](int buf, int t) {
        #pragma unroll
        for (int it = 0; it < 2; ++it) {
            int d = srow + it * 32;
            const u16* src = VT + ((size_t)bh * kDK + d) * kL + t * 64 + ((sc ^ (d & 7)) << 3);
            gll16(src, &Vsh[buf][it * 2048 + w * 512]);
        }
    };
    auto stageW = [&](int buf, int c) {
        #pragma unroll
        for (int it = 0; it < 2; ++it) {
            int r = srow + it * 32;
            long row = (long)i0 + 64L * c + r;
            if (row > kWrelMax) row = kWrelMax;
            gll16(Wr + row * 64 + ((sc ^ (r & 7)) << 3), &Wsh[buf][it * 2048 + w * 512]);
        }
    };

    // ---- hoisted LDS fragment offsets ----
    int foff[4][2];                 // K/V/W fragment reads
    #pragma unroll
    for (int n = 0; n < 4; ++n)
        #pragma unroll
        for (int ks = 0; ks < 2; ++ks) {
            int row = n * 16 + s;
            foff[n][ks] = row * 64 + (((ks * 4 + g) ^ (row & 7)) << 3);
        }
    int prd[2];                     // Ps A-fragment reads (rows i=s)
    #pragma unroll
    for (int ks = 0; ks < 2; ++ks)
        prd[ks] = s * 64 + (((ks * 4 + g) ^ (s & 7)) << 3);
    int pwr[4];                     // Ps b64 writes: row i=s, j=16jn+4g..+3
    #pragma unroll
    for (int jn = 0; jn < 4; ++jn) {
        int c = 2 * jn + (g >> 1);
        pwr[jn] = s * 64 + ((c ^ (s & 7)) << 3) + (g & 1) * 4;
    }

    // Q fragments (pre-scaled by 0.125*log2e in projection)
    const size_t qbase = ((size_t)bh * kL + i0 + w * 16 + s) * kDK + g * 8;
    bf16x8 qh[2];
    qh[0] = *(const bf16x8*)&Qh[qbase];
    qh[1] = *(const bf16x8*)&Qh[qbase + 32];

    const f32x4 fz = {0.f, 0.f, 0.f, 0.f};
    const int ilS = w * 16 + s;       // Tb read row
    const int ilw = w * 16 + g * 4;   // Tb write base row

    // T-gemm: T[il][u] stored at Tb[il][key=(u_loc-il)&127]; rows wave-private
    auto computeT = [&](int c, int buf) {
        f32x4 tacc[4];
        #pragma unroll
        for (int un = 0; un < 4; ++un) {
            bf16x8 wf0 = *(const bf16x8*)&Wsh[buf][foff[un][0]];
            bf16x8 wf1 = *(const bf16x8*)&Wsh[buf][foff[un][1]];
            tacc[un] = MFMA(qh[0], wf0, fz);
            tacc[un] = MFMA(qh[1], wf1, tacc[un]);
        }
        const int cb = c * 64 - w * 16 + s - g * 4;
        #pragma unroll
        for (int un = 0; un < 4; ++un)
            #pragma unroll
            for (int r = 0; r < 4; ++r) {
                int key = (cb + un * 16 - r) & 127;
                Tb[(ilw + r) * 132 + key] =
                    (u16)(__float_as_uint(tacc[un][r]) >> 16);
            }
    };

    f32x4 sacc[4];
    auto loadBias = [&](int t) {
        #pragma unroll
        for (int jn = 0; jn < 4; ++jn) {
            int kb = (t * 64 + jn * 16 + g * 4) & 127;   // 4-aligned
            uint2 tw = *(const uint2*)&Tb[ilS * 132 + kb];
            sacc[jn][0] = __uint_as_float(tw.x << 16);
            sacc[jn][1] = __uint_as_float(tw.x & 0xFFFF0000u);
            sacc[jn][2] = __uint_as_float(tw.y << 16);
            sacc[jn][3] = __uint_as_float(tw.y & 0xFFFF0000u);
        }
    };

    bf16x8 ones;
    #pragma unroll
    for (int q = 0; q < 8; ++q) ones[q] = (short)0x3F80;

    // prologue
    stageK(0, 0); stageV(0, 0); stageW(0, 0); stageW(1, 1);
    __syncthreads();                        // W0,W1,K0,V0 landed
    computeT(0, 0); computeT(1, 1);
    loadBias(0);                            // own-wave rows, program-ordered
    __syncthreads();                        // all waves done reading Wsh[0/1]
    stageW(0, 2);                           // chunk 2 into buf 0
    __syncthreads();                        // chunk-2 W landed

    f32x4 oacc[4] = {fz, fz, fz, fz};
    f32x4 lacc = fz;

    for (int t = 0; t < 32; ++t) {
        const int cur = t & 1, nxt = cur ^ 1;
        if (t < 31) { stageK(nxt, t + 1); stageV(nxt, t + 1); }
        if (t < 30) stageW(nxt, t + 3);     // buf (t+3)&1 == nxt
        if (t < 31) computeT(t + 2, cur);   // chunk t+2 staged at t-1 into buf t&1

        // ---- S^T = K Q^T + bias (sacc preloaded last tile) ----
        __builtin_amdgcn_s_setprio(1);
        #pragma unroll
        for (int jn = 0; jn < 4; ++jn)
            #pragma unroll
            for (int ks = 0; ks < 2; ++ks) {
                bf16x8 kf = *(const bf16x8*)&Ksh[cur][foff[jn][ks]];
                sacc[jn] = MFMA(kf, qh[ks], sacc[jn]);
            }
        __builtin_amdgcn_s_setprio(0);

        // ---- p = exp2(s); trunc-pack pairs; one b64 write per jn ----
        #pragma unroll
        for (int jn = 0; jn < 4; ++jn) {
            u32 a0 = __float_as_uint(fexp2(sacc[jn][0])) & 0xFFFF0000u;
            u32 a1 = __float_as_uint(fexp2(sacc[jn][1])) & 0xFFFF0000u;
            u32 a2 = __float_as_uint(fexp2(sacc[jn][2])) & 0xFFFF0000u;
            u32 a3 = __float_as_uint(fexp2(sacc[jn][3])) & 0xFFFF0000u;
            uint2 pw;
            pw.x = a1 | (a0 >> 16);   // lo u16 = p0 (col j), hi u16 = p1
            pw.y = a3 | (a2 >> 16);
            *(uint2*)&Ps[w][pwr[jn]] = pw;
        }

        // ---- prefetch next tile's bias into sacc (dead after exp2) ----
        if (t < 31) loadBias(t + 1);

        // ---- O += P V;  l += P * ones ----
        __builtin_amdgcn_s_setprio(1);
        #pragma unroll
        for (int ks = 0; ks < 2; ++ks) {
            bf16x8 pf = *(const bf16x8*)&Ps[w][prd[ks]];
            lacc = MFMA(pf, ones, lacc);
            #pragma unroll
            for (int dn = 0; dn < 4; ++dn) {
                bf16x8 vf = *(const bf16x8*)&Vsh[cur][foff[dn][ks]];
                oacc[dn] = MFMA(pf, vf, oacc[dn]);
            }
        }
        __builtin_amdgcn_s_setprio(0);
        __syncthreads();   // drains gll issued this tile; releases cur bufs
    }

    // ---- epilogue: lacc[r] is already l[i = w*16 + g*4 + r] ----
    float invr[4];
    #pragma unroll
    for (int r = 0; r < 4; ++r) invr[r] = 1.0f / lacc[r];

    #pragma unroll
    for (int dn = 0; dn < 4; ++dn)
        #pragma unroll
        for (int r = 0; r < 4; ++r) {
            const int ig = i0 + w * 16 + g * 4 + r;
            float val = oacc[dn][r] * invr[r];
            u16 hh, ll; splitf(val, hh, ll);
            size_t o = ((size_t)(b * kL + ig)) * kD + h * kDK + dn * 16 + s;
            Ch[o] = hh; Cl[o] = ll;
        }
}

// ---------------------------------------------------------------------------
extern "C" void kernel_launch(void* const* d_in, const int* in_sizes, int n_in,
                              void* d_out, int out_size, void* d_ws, size_t ws_size,
                              hipStream_t stream) {
    const float* q    = (const float*)d_in[0];
    const float* k    = (const float*)d_in[1];
    const float* v    = (const float*)d_in[2];
    const float* Wq   = (const float*)d_in[3];
    const float* bq   = (const float*)d_in[4];
    const float* Wk   = (const float*)d_in[5];
    const float* bk   = (const float*)d_in[6];
    const float* Wv   = (const float*)d_in[7];
    const float* bv   = (const float*)d_in[8];
    const float* Wo   = (const float*)d_in[9];
    const float* bo   = (const float*)d_in[10];
    const float* wrel = (const float*)d_in[11];
    float* out = (float*)d_out;

    u16* p = (u16*)d_ws;
    const size_t nW = (size_t)kD * kD;
    const size_t nR = (size_t)(2 * kL - 1) * kDK;
    const size_t nT = (size_t)kB * kL * kD;
    u16* wqh = p; p += nW;  u16* wql = p; p += nW;
    u16* wkh = p; p += nW;  u16* wkl = p; p += nW;
    u16* wvh = p; p += nW;  u16* wvl = p; p += nW;
    u16* woh = p; p += nW;  u16* wol = p; p += nW;
    u16* wrh = p; p += nR;  u16* wrl = p; p += nR;
    u16* qhh = p; p += nT;
    u16* khh = p; p += nT;
    u16* vT  = p; p += nT;
    u16* cch = p; p += nT;  u16* ccl = p; p += nT;

    // K1: weight splits (4 fused) + w_rel split
    hipLaunchKernelGGL(split4x4_kernel, dim3(1024, 4), dim3(256), 0, stream,
                       Wq, Wk, Wv, Wo, wqh, wkh, wvh, woh, wql, wkl, wvl, wol,
                       (int)(nW / 4));
    hipLaunchKernelGGL(split4_kernel, dim3(256), dim3(256), 0, stream,
                       wrel, wrh, wrl, (int)(nR / 4));

    dim3 blk(256);
    // K2: merged Q/K/V projections
    hipLaunchKernelGGL(proj3, dim3(kR / 128, kD / 128, 3), blk, 0, stream,
                       q, k, v, wqh, wkh, wvh, bq, bk, bv, qhh, khh, vT);

    // K3: attention
    hipLaunchKernelGGL(attn3, dim3(kL / 64, kB * kH), blk, 0, stream,
                       qhh, khh, vT, wrh, cch, ccl);

    // K4: output projection
    hipLaunchKernelGGL(out_gemm, dim3(kR / 128, kD / 128), blk, 0, stream,
                       cch, ccl, woh, wol, bo, out);
}

// Round 17
// 361.699 us; speedup vs baseline: 1.1636x; 1.0242x over previous
//
#include <hip/hip_runtime.h>

typedef __attribute__((ext_vector_type(8))) short bf16x8;
typedef __attribute__((ext_vector_type(4))) float f32x4;
typedef unsigned short u16;
typedef unsigned int u32;

constexpr int kB = 4, kL = 2048, kD = 1024, kH = 16, kDK = 64;
constexpr int kR = kB * kL;
constexpr long kWrelMax = 2 * kL - 2;   // 4094 = last valid w_rel row
constexpr float kQScale = 0.125f * 1.44269504088896f;  // 1/sqrt(dk) * log2(e)

__device__ inline float fexp2(float x) { return __builtin_amdgcn_exp2f(x); }

__device__ inline u16 f2bf(float x) {
    union { float f; u32 u; } v; v.f = x;
    u32 r = v.u + 0x7FFFu + ((v.u >> 16) & 1u);   // RNE
    return (u16)(r >> 16);
}
// trunc split: hi = trunc_bf16(x), lo = trunc_bf16(x - hi)
__device__ inline void splitf(float x, u16& hi, u16& lo) {
    union { float f; u32 u; } v; v.f = x;
    u32 hu = v.u & 0xFFFF0000u;
    hi = (u16)(hu >> 16);
    union { u32 u; float f; } hf; hf.u = hu;
    union { float f; u32 u; } l; l.f = x - hf.f;
    lo = (u16)(l.u >> 16);
}
__device__ inline f32x4 MFMA(bf16x8 a, bf16x8 b, f32x4 c) {
    return __builtin_amdgcn_mfma_f32_16x16x32_bf16(a, b, c, 0, 0, 0);
}
// async global->LDS, 16B per lane; LDS dest = wave-uniform base + lane*16
__device__ __forceinline__ void gll16(const u16* g, u16* l) {
    __builtin_amdgcn_global_load_lds(
        (const __attribute__((address_space(1))) u32*)g,
        (__attribute__((address_space(3))) u32*)l, 16, 0, 0);
}

// ---------------------------------------------------------------------------
// K1: fp32 -> bf16 hi/lo split; 4 tensors in one launch (blockIdx.y selects)
// ---------------------------------------------------------------------------
__global__ void split4x4_kernel(const float* __restrict__ i0, const float* __restrict__ i1,
                                const float* __restrict__ i2, const float* __restrict__ i3,
                                u16* __restrict__ h0, u16* __restrict__ h1,
                                u16* __restrict__ h2, u16* __restrict__ h3,
                                u16* __restrict__ l0, u16* __restrict__ l1,
                                u16* __restrict__ l2, u16* __restrict__ l3, int n4) {
    int idx = blockIdx.x * blockDim.x + threadIdx.x;
    if (idx >= n4) return;
    const float* in = blockIdx.y == 0 ? i0 : blockIdx.y == 1 ? i1 : blockIdx.y == 2 ? i2 : i3;
    u16* hi = blockIdx.y == 0 ? h0 : blockIdx.y == 1 ? h1 : blockIdx.y == 2 ? h2 : h3;
    u16* lo = blockIdx.y == 0 ? l0 : blockIdx.y == 1 ? l1 : blockIdx.y == 2 ? l2 : l3;
    float4 x = reinterpret_cast<const float4*>(in)[idx];
    ushort4 h, l;
    splitf(x.x, h.x, l.x); splitf(x.y, h.y, l.y);
    splitf(x.z, h.z, l.z); splitf(x.w, h.w, l.w);
    reinterpret_cast<ushort4*>(hi)[idx] = h;
    reinterpret_cast<ushort4*>(lo)[idx] = l;
}
__global__ void split4_kernel(const float* __restrict__ in,
                              u16* __restrict__ hi, u16* __restrict__ lo, int n4) {
    int idx = blockIdx.x * blockDim.x + threadIdx.x;
    if (idx >= n4) return;
    float4 x = reinterpret_cast<const float4*>(in)[idx];
    ushort4 h, l;
    splitf(x.x, h.x, l.x); splitf(x.y, h.y, l.y);
    splitf(x.z, h.z, l.z); splitf(x.w, h.w, l.w);
    reinterpret_cast<ushort4*>(hi)[idx] = h;
    reinterpret_cast<ushort4*>(lo)[idx] = l;
}

// ---------------------------------------------------------------------------
// K2: merged Q/K/V projection GEMM (blockIdx.z selects). 2-term exact-A.
//  R12-proven reg-staged structure (2 barriers/K-step, loads 1 iter ahead).
// ---------------------------------------------------------------------------
__global__ __launch_bounds__(256) void proj3(
    const float* __restrict__ Aq, const float* __restrict__ Ak, const float* __restrict__ Av,
    const u16* __restrict__ Bqh, const u16* __restrict__ Bkh, const u16* __restrict__ Bvh,
    const float* __restrict__ bq, const float* __restrict__ bk, const float* __restrict__ bv,
    u16* __restrict__ Yq, u16* __restrict__ Yk, u16* __restrict__ Yv)
{
    __shared__ __align__(16) u16 Ash[128 * 32], Asl[128 * 32];
    __shared__ __align__(16) u16 Bsh[128 * 32];

    const int z = blockIdx.z;
    const float* Af32 = z == 0 ? Aq : z == 1 ? Ak : Av;
    const u16* Bgh    = z == 0 ? Bqh : z == 1 ? Bkh : Bvh;
    const float* bias = z == 0 ? bq : z == 1 ? bk : bv;
    u16* Yh           = z == 0 ? Yq : z == 1 ? Yk : Yv;
    const float scale = z == 0 ? kQScale : 1.0f;

    const int tid = threadIdx.x;
    const int row0 = blockIdx.x * 128, col0 = blockIdx.y * 128;
    const int w = tid >> 6, lane = tid & 63;
    const int s = lane & 15, g = lane >> 4;
    const int wrow = w >> 1, wcol = w & 1;
    const int srow = tid >> 1;
    const int skq  = (tid & 1) * 16;

    const f32x4 fz = {0.f, 0.f, 0.f, 0.f};
    f32x4 acc[4][4];
    #pragma unroll
    for (int m = 0; m < 4; ++m)
        #pragma unroll
        for (int n = 0; n < 4; ++n) acc[m][n] = fz;

    float4 aR[4];
    bf16x8 bRh[2];

    auto loadA = [&](int k0) {
        const float* p = &Af32[(size_t)(row0 + srow) * kD + k0 + skq];
        aR[0] = *(const float4*)(p);
        aR[1] = *(const float4*)(p + 4);
        aR[2] = *(const float4*)(p + 8);
        aR[3] = *(const float4*)(p + 12);
    };
    auto loadB = [&](int k0) {
        const u16* ph = &Bgh[(size_t)(col0 + srow) * kD + k0 + skq];
        bRh[0] = *(const bf16x8*)ph; bRh[1] = *(const bf16x8*)(ph + 8);
    };
    auto writeAB = [&]() {
        const int c0 = skq >> 3, sw = srow & 3;
        bf16x8 h0, h1, l0, l1;
        const float* af = (const float*)aR;
        #pragma unroll
        for (int q = 0; q < 8; ++q) {
            u16 hh, ll;
            splitf(af[q], hh, ll);     h0[q] = (short)hh; l0[q] = (short)ll;
            splitf(af[8 + q], hh, ll); h1[q] = (short)hh; l1[q] = (short)ll;
        }
        *(bf16x8*)&Ash[srow * 32 + (((c0    ) ^ sw) << 3)] = h0;
        *(bf16x8*)&Ash[srow * 32 + (((c0 + 1) ^ sw) << 3)] = h1;
        *(bf16x8*)&Asl[srow * 32 + (((c0    ) ^ sw) << 3)] = l0;
        *(bf16x8*)&Asl[srow * 32 + (((c0 + 1) ^ sw) << 3)] = l1;
        *(bf16x8*)&Bsh[srow * 32 + (((c0    ) ^ sw) << 3)] = bRh[0];
        *(bf16x8*)&Bsh[srow * 32 + (((c0 + 1) ^ sw) << 3)] = bRh[1];
    };

    loadA(0); loadB(0);
    for (int k0 = 0; k0 < kD; k0 += 32) {
        __syncthreads();
        writeAB();
        __syncthreads();
        if (k0 + 32 < kD) { loadA(k0 + 32); loadB(k0 + 32); }

        bf16x8 fAh[4], fAl[4], fBh[4];
        #pragma unroll
        for (int m = 0; m < 4; ++m) {
            int ar = wrow * 64 + m * 16 + s;
            int off = ar * 32 + ((g ^ (ar & 3)) << 3);
            fAh[m] = *(const bf16x8*)&Ash[off];
            fAl[m] = *(const bf16x8*)&Asl[off];
        }
        #pragma unroll
        for (int n = 0; n < 4; ++n) {
            int bc = wcol * 64 + n * 16 + s;
            int off = bc * 32 + ((g ^ (bc & 3)) << 3);
            fBh[n] = *(const bf16x8*)&Bsh[off];
        }
        #pragma unroll
        for (int m = 0; m < 4; ++m)
            #pragma unroll
            for (int n = 0; n < 4; ++n) {
                acc[m][n] = MFMA(fAh[m], fBh[n], acc[m][n]);
                acc[m][n] = MFMA(fAl[m], fBh[n], acc[m][n]);
            }
    }

    #pragma unroll
    for (int n = 0; n < 4; ++n) {
        const int colg = col0 + wcol * 64 + n * 16 + s;
        const float bv = bias[colg];
        #pragma unroll
        for (int m = 0; m < 4; ++m) {
            const int rowg = row0 + wrow * 64 + m * 16 + (g << 2);
            if (z == 2) {
                const int b = rowg >> 11, i = rowg & (kL - 1);
                const int h = colg >> 6, d = colg & 63;
                ushort4 o4;
                o4.x = f2bf(acc[m][n][0] + bv);
                o4.y = f2bf(acc[m][n][1] + bv);
                o4.z = f2bf(acc[m][n][2] + bv);
                o4.w = f2bf(acc[m][n][3] + bv);
                *(ushort4*)&Yh[(((size_t)b * kH + h) * kDK + d) * kL + i] = o4;
            } else {
                #pragma unroll
                for (int r = 0; r < 4; ++r) {
                    float val = (acc[m][n][r] + bv) * scale;
                    const int rg = rowg + r;
                    const int b = rg >> 11, i = rg & (kL - 1);
                    const int h = colg >> 6, d = colg & 63;
                    Yh[(((size_t)b * kH + h) * kL + i) * kDK + d] = f2bf(val);
                }
            }
        }
    }
}

// ---------------------------------------------------------------------------
// K4: output GEMM  out = concat @ Wo^T + bo  (3-term, fp32 out)
//  R12-proven reg-staged structure.
// ---------------------------------------------------------------------------
__global__ __launch_bounds__(256) void out_gemm(
    const u16* __restrict__ Agh, const u16* __restrict__ Agl,
    const u16* __restrict__ Bgh, const u16* __restrict__ Bgl,
    const float* __restrict__ bias, float* __restrict__ Yf)
{
    __shared__ __align__(16) u16 Ash[128 * 32], Asl[128 * 32];
    __shared__ __align__(16) u16 Bsh[128 * 32], Bsl[128 * 32];

    const int tid = threadIdx.x;
    const int row0 = blockIdx.x * 128, col0 = blockIdx.y * 128;
    const int w = tid >> 6, lane = tid & 63;
    const int s = lane & 15, g = lane >> 4;
    const int wrow = w >> 1, wcol = w & 1;
    const int srow = tid >> 1;
    const int skq  = (tid & 1) * 16;

    const f32x4 fz = {0.f, 0.f, 0.f, 0.f};
    f32x4 acc[4][4];
    #pragma unroll
    for (int m = 0; m < 4; ++m)
        #pragma unroll
        for (int n = 0; n < 4; ++n) acc[m][n] = fz;

    bf16x8 aRh[2], aRl[2], bRh[2], bRl[2];
    auto loadA = [&](int k0) {
        const u16* ph = &Agh[(size_t)(row0 + srow) * kD + k0 + skq];
        const u16* pl = &Agl[(size_t)(row0 + srow) * kD + k0 + skq];
        aRh[0] = *(const bf16x8*)ph; aRh[1] = *(const bf16x8*)(ph + 8);
        aRl[0] = *(const bf16x8*)pl; aRl[1] = *(const bf16x8*)(pl + 8);
    };
    auto loadB = [&](int k0) {
        const u16* ph = &Bgh[(size_t)(col0 + srow) * kD + k0 + skq];
        const u16* pl = &Bgl[(size_t)(col0 + srow) * kD + k0 + skq];
        bRh[0] = *(const bf16x8*)ph; bRh[1] = *(const bf16x8*)(ph + 8);
        bRl[0] = *(const bf16x8*)pl; bRl[1] = *(const bf16x8*)(pl + 8);
    };
    auto writeAB = [&]() {
        const int c0 = skq >> 3, sw = srow & 3;
        *(bf16x8*)&Ash[srow * 32 + (((c0    ) ^ sw) << 3)] = aRh[0];
        *(bf16x8*)&Ash[srow * 32 + (((c0 + 1) ^ sw) << 3)] = aRh[1];
        *(bf16x8*)&Asl[srow * 32 + (((c0    ) ^ sw) << 3)] = aRl[0];
        *(bf16x8*)&Asl[srow * 32 + (((c0 + 1) ^ sw) << 3)] = aRl[1];
        *(bf16x8*)&Bsh[srow * 32 + (((c0    ) ^ sw) << 3)] = bRh[0];
        *(bf16x8*)&Bsh[srow * 32 + (((c0 + 1) ^ sw) << 3)] = bRh[1];
        *(bf16x8*)&Bsl[srow * 32 + (((c0    ) ^ sw) << 3)] = bRl[0];
        *(bf16x8*)&Bsl[srow * 32 + (((c0 + 1) ^ sw) << 3)] = bRl[1];
    };

    loadA(0); loadB(0);
    for (int k0 = 0; k0 < kD; k0 += 32) {
        __syncthreads();
        writeAB();
        __syncthreads();
        if (k0 + 32 < kD) { loadA(k0 + 32); loadB(k0 + 32); }

        bf16x8 fAh[4], fAl[4], fBh[4], fBl[4];
        #pragma unroll
        for (int m = 0; m < 4; ++m) {
            int ar = wrow * 64 + m * 16 + s;
            int off = ar * 32 + ((g ^ (ar & 3)) << 3);
            fAh[m] = *(const bf16x8*)&Ash[off];
            fAl[m] = *(const bf16x8*)&Asl[off];
        }
        #pragma unroll
        for (int n = 0; n < 4; ++n) {
            int bc = wcol * 64 + n * 16 + s;
            int off = bc * 32 + ((g ^ (bc & 3)) << 3);
            fBh[n] = *(const bf16x8*)&Bsh[off];
            fBl[n] = *(const bf16x8*)&Bsl[off];
        }
        #pragma unroll
        for (int m = 0; m < 4; ++m)
            #pragma unroll
            for (int n = 0; n < 4; ++n) {
                acc[m][n] = MFMA(fAh[m], fBh[n], acc[m][n]);
                acc[m][n] = MFMA(fAl[m], fBh[n], acc[m][n]);
                acc[m][n] = MFMA(fAh[m], fBl[n], acc[m][n]);
            }
    }

    #pragma unroll
    for (int n = 0; n < 4; ++n) {
        const int colg = col0 + wcol * 64 + n * 16 + s;
        const float bv = bias[colg];
        #pragma unroll
        for (int m = 0; m < 4; ++m) {
            const int rowg = row0 + wrow * 64 + m * 16 + (g << 2);
            #pragma unroll
            for (int r = 0; r < 4; ++r)
                Yf[(size_t)(rowg + r) * kD + colg] = acc[m][n][r] + bv;
        }
    }
}

// ---------------------------------------------------------------------------
// K3: flash attention. R16 structure + critical-path reorder: QK fires
//     immediately at the barrier; computeT(t+2)+loadBias(t+1) moved into the
//     exp2->PV dependency gap (independent MFMA/LDS work overlaps the Ps
//     write->read latency). Hazards unchanged: Tb rows wave-private, Wsh
//     buffer parity identical, one barrier per tile.
// ---------------------------------------------------------------------------
__global__ __launch_bounds__(256, 2) void attn3(
    const u16* __restrict__ Qh,
    const u16* __restrict__ Kg, const u16* __restrict__ VT,
    const u16* __restrict__ Wr,
    u16* __restrict__ Ch, u16* __restrict__ Cl)
{
    __shared__ __align__(16) u16 Ksh[2][64 * 64];   // [j][d] swizzled     16 KB
    __shared__ __align__(16) u16 Vsh[2][64 * 64];   // V^T [d][j] swizzled 16 KB
    __shared__ __align__(16) u16 Wsh[2][64 * 64];   // [u_loc][d] swizzled 16 KB
    __shared__ __align__(16) u16 Ps[4][16 * 64];    // per-wave P[i][j]     8 KB
    __shared__ __align__(16) u16 Tb[64 * 132];      // bias [il][key]    16.5 KB

    const int tid = threadIdx.x;
    const int w = tid >> 6, lane = tid & 63;
    const int s = lane & 15, g = lane >> 4;
    const int pb = blockIdx.x + 32 * blockIdx.y;    // physical block id
    const int lb = (pb & 7) * 256 + (pb >> 3);      // bijective XCD swizzle
    const int bh = lb >> 5, i0 = (lb & 31) * 64;
    const int b = bh >> 4, h = bh & 15;

    const int srow = tid >> 3;      // staging: dest row (tid>>3)+32*it
    const int sc = tid & 7;         // dest 16B chunk

    auto stageK = [&](int buf, int t) {
        const u16* base = Kg + ((size_t)bh * kL + (size_t)t * 64) * kDK;
        #pragma unroll
        for (int it = 0; it < 2; ++it) {
            int r = srow + it * 32;
            gll16(base + r * 64 + ((sc ^ (r & 7)) << 3), &Ksh[buf][it * 2048 + w * 512]);
        }
    };
    auto stageV = [&](int buf, int t) {
        #pragma unroll
        for (int it = 0; it < 2; ++it) {
            int d = srow + it * 32;
            const u16* src = VT + ((size_t)bh * kDK + d) * kL + t * 64 + ((sc ^ (d & 7)) << 3);
            gll16(src, &Vsh[buf][it * 2048 + w * 512]);
        }
    };
    auto stageW = [&](int buf, int c) {
        #pragma unroll
        for (int it = 0; it < 2; ++it) {
            int r = srow + it * 32;
            long row = (long)i0 + 64L * c + r;
            if (row > kWrelMax) row = kWrelMax;
            gll16(Wr + row * 64 + ((sc ^ (r & 7)) << 3), &Wsh[buf][it * 2048 + w * 512]);
        }
    };

    // ---- hoisted LDS fragment offsets ----
    int foff[4][2];                 // K/V/W fragment reads
    #pragma unroll
    for (int n = 0; n < 4; ++n)
        #pragma unroll
        for (int ks = 0; ks < 2; ++ks) {
            int row = n * 16 + s;
            foff[n][ks] = row * 64 + (((ks * 4 + g) ^ (row & 7)) << 3);
        }
    int prd[2];                     // Ps A-fragment reads (rows i=s)
    #pragma unroll
    for (int ks = 0; ks < 2; ++ks)
        prd[ks] = s * 64 + (((ks * 4 + g) ^ (s & 7)) << 3);
    int pwr[4];                     // Ps b64 writes: row i=s, j=16jn+4g..+3
    #pragma unroll
    for (int jn = 0; jn < 4; ++jn) {
        int c = 2 * jn + (g >> 1);
        pwr[jn] = s * 64 + ((c ^ (s & 7)) << 3) + (g & 1) * 4;
    }

    // Q fragments (pre-scaled by 0.125*log2e in projection)
    const size_t qbase = ((size_t)bh * kL + i0 + w * 16 + s) * kDK + g * 8;
    bf16x8 qh[2];
    qh[0] = *(const bf16x8*)&Qh[qbase];
    qh[1] = *(const bf16x8*)&Qh[qbase + 32];

    const f32x4 fz = {0.f, 0.f, 0.f, 0.f};
    const int ilS = w * 16 + s;       // Tb read row
    const int ilw = w * 16 + g * 4;   // Tb write base row

    // T-gemm: T[il][u] stored at Tb[il][key=(u_loc-il)&127]; rows wave-private
    auto computeT = [&](int c, int buf) {
        f32x4 tacc[4];
        #pragma unroll
        for (int un = 0; un < 4; ++un) {
            bf16x8 wf0 = *(const bf16x8*)&Wsh[buf][foff[un][0]];
            bf16x8 wf1 = *(const bf16x8*)&Wsh[buf][foff[un][1]];
            tacc[un] = MFMA(qh[0], wf0, fz);
            tacc[un] = MFMA(qh[1], wf1, tacc[un]);
        }
        const int cb = c * 64 - w * 16 + s - g * 4;
        #pragma unroll
        for (int un = 0; un < 4; ++un)
            #pragma unroll
            for (int r = 0; r < 4; ++r) {
                int key = (cb + un * 16 - r) & 127;
                Tb[(ilw + r) * 132 + key] =
                    (u16)(__float_as_uint(tacc[un][r]) >> 16);
            }
    };

    f32x4 sacc[4];
    auto loadBias = [&](int t) {
        #pragma unroll
        for (int jn = 0; jn < 4; ++jn) {
            int kb = (t * 64 + jn * 16 + g * 4) & 127;   // 4-aligned
            uint2 tw = *(const uint2*)&Tb[ilS * 132 + kb];
            sacc[jn][0] = __uint_as_float(tw.x << 16);
            sacc[jn][1] = __uint_as_float(tw.x & 0xFFFF0000u);
            sacc[jn][2] = __uint_as_float(tw.y << 16);
            sacc[jn][3] = __uint_as_float(tw.y & 0xFFFF0000u);
        }
    };

    bf16x8 ones;
    #pragma unroll
    for (int q = 0; q < 8; ++q) ones[q] = (short)0x3F80;

    // prologue
    stageK(0, 0); stageV(0, 0); stageW(0, 0); stageW(1, 1);
    __syncthreads();                        // W0,W1,K0,V0 landed
    computeT(0, 0); computeT(1, 1);
    loadBias(0);                            // own-wave rows, program-ordered
    __syncthreads();                        // all waves done reading Wsh[0/1]
    stageW(0, 2);                           // chunk 2 into buf 0
    __syncthreads();                        // chunk-2 W landed

    f32x4 oacc[4] = {fz, fz, fz, fz};
    f32x4 lacc = fz;

    #pragma unroll 2
    for (int t = 0; t < 32; ++t) {
        const int cur = t & 1, nxt = cur ^ 1;
        if (t < 31) { stageK(nxt, t + 1); stageV(nxt, t + 1); }
        if (t < 30) stageW(nxt, t + 3);     // buf (t+3)&1 == nxt

        // ---- S^T = K Q^T + bias (sacc preloaded last tile) — fires at once
        __builtin_amdgcn_s_setprio(1);
        #pragma unroll
        for (int jn = 0; jn < 4; ++jn)
            #pragma unroll
            for (int ks = 0; ks < 2; ++ks) {
                bf16x8 kf = *(const bf16x8*)&Ksh[cur][foff[jn][ks]];
                sacc[jn] = MFMA(kf, qh[ks], sacc[jn]);
            }
        __builtin_amdgcn_s_setprio(0);

        // ---- p = exp2(s); trunc-pack pairs; one b64 write per jn ----
        #pragma unroll
        for (int jn = 0; jn < 4; ++jn) {
            u32 a0 = __float_as_uint(fexp2(sacc[jn][0])) & 0xFFFF0000u;
            u32 a1 = __float_as_uint(fexp2(sacc[jn][1])) & 0xFFFF0000u;
            u32 a2 = __float_as_uint(fexp2(sacc[jn][2])) & 0xFFFF0000u;
            u32 a3 = __float_as_uint(fexp2(sacc[jn][3])) & 0xFFFF0000u;
            uint2 pw;
            pw.x = a1 | (a0 >> 16);   // lo u16 = p0 (col j), hi u16 = p1
            pw.y = a3 | (a2 >> 16);
            *(uint2*)&Ps[w][pwr[jn]] = pw;
        }

        // ---- independent work fills the exp2->PV gap ----
        if (t < 31) computeT(t + 2, cur);   // chunk t+2 staged at t-1, buf t&1
        if (t < 31) loadBias(t + 1);        // chunks t+1 (@t-1), t+2 (just now)

        // ---- O += P V;  l += P * ones ----
        __builtin_amdgcn_s_setprio(1);
        #pragma unroll
        for (int ks = 0; ks < 2; ++ks) {
            bf16x8 pf = *(const bf16x8*)&Ps[w][prd[ks]];
            lacc = MFMA(pf, ones, lacc);
            #pragma unroll
            for (int dn = 0; dn < 4; ++dn) {
                bf16x8 vf = *(const bf16x8*)&Vsh[cur][foff[dn][ks]];
                oacc[dn] = MFMA(pf, vf, oacc[dn]);
            }
        }
        __builtin_amdgcn_s_setprio(0);
        __syncthreads();   // drains gll issued this tile; releases cur bufs
    }

    // ---- epilogue: lacc[r] is already l[i = w*16 + g*4 + r] ----
    float invr[4];
    #pragma unroll
    for (int r = 0; r < 4; ++r) invr[r] = 1.0f / lacc[r];

    #pragma unroll
    for (int dn = 0; dn < 4; ++dn)
        #pragma unroll
        for (int r = 0; r < 4; ++r) {
            const int ig = i0 + w * 16 + g * 4 + r;
            float val = oacc[dn][r] * invr[r];
            u16 hh, ll; splitf(val, hh, ll);
            size_t o = ((size_t)(b * kL + ig)) * kD + h * kDK + dn * 16 + s;
            Ch[o] = hh; Cl[o] = ll;
        }
}

// ---------------------------------------------------------------------------
extern "C" void kernel_launch(void* const* d_in, const int* in_sizes, int n_in,
                              void* d_out, int out_size, void* d_ws, size_t ws_size,
                              hipStream_t stream) {
    const float* q    = (const float*)d_in[0];
    const float* k    = (const float*)d_in[1];
    const float* v    = (const float*)d_in[2];
    const float* Wq   = (const float*)d_in[3];
    const float* bq   = (const float*)d_in[4];
    const float* Wk   = (const float*)d_in[5];
    const float* bk   = (const float*)d_in[6];
    const float* Wv   = (const float*)d_in[7];
    const float* bv   = (const float*)d_in[8];
    const float* Wo   = (const float*)d_in[9];
    const float* bo   = (const float*)d_in[10];
    const float* wrel = (const float*)d_in[11];
    float* out = (float*)d_out;

    u16* p = (u16*)d_ws;
    const size_t nW = (size_t)kD * kD;
    const size_t nR = (size_t)(2 * kL - 1) * kDK;
    const size_t nT = (size_t)kB * kL * kD;
    u16* wqh = p; p += nW;  u16* wql = p; p += nW;
    u16* wkh = p; p += nW;  u16* wkl = p; p += nW;
    u16* wvh = p; p += nW;  u16* wvl = p; p += nW;
    u16* woh = p; p += nW;  u16* wol = p; p += nW;
    u16* wrh = p; p += nR;  u16* wrl = p; p += nR;
    u16* qhh = p; p += nT;
    u16* khh = p; p += nT;
    u16* vT  = p; p += nT;
    u16* cch = p; p += nT;  u16* ccl = p; p += nT;

    // K1: weight splits (4 fused) + w_rel split
    hipLaunchKernelGGL(split4x4_kernel, dim3(1024, 4), dim3(256), 0, stream,
                       Wq, Wk, Wv, Wo, wqh, wkh, wvh, woh, wql, wkl, wvl, wol,
                       (int)(nW / 4));
    hipLaunchKernelGGL(split4_kernel, dim3(256), dim3(256), 0, stream,
                       wrel, wrh, wrl, (int)(nR / 4));

    dim3 blk(256);
    // K2: merged Q/K/V projections
    hipLaunchKernelGGL(proj3, dim3(kR / 128, kD / 128, 3), blk, 0, stream,
                       q, k, v, wqh, wkh, wvh, bq, bk, bv, qhh, khh, vT);

    // K3: attention
    hipLaunchKernelGGL(attn3, dim3(kL / 64, kB * kH), blk, 0, stream,
                       qhh, khh, vT, wrh, cch, ccl);

    // K4: output projection
    hipLaunchKernelGGL(out_gemm, dim3(kR / 128, kD / 128), blk, 0, stream,
                       cch, ccl, woh, wol, bo, out);
}